// Round 5
// baseline (5034.324 us; speedup 1.0000x reference)
//
#include <hip/hip_runtime.h>
#include <hip/hip_bf16.h>
#include <math.h>

// All inputs fp32, output fp32, workspace fp32. fp32 math throughout.

// ---------------------------------------------------------------------------
// GEMM: C[M,N] = act(A[M,K] @ W[N,K]^T + bias[N]); EPI: 0=none, 1=exact GELU
// BM=BN=64, BK=32, 256 threads, 4x4 per thread. M%64==0, N%64==0, K%32==0.
// ---------------------------------------------------------------------------
template <int EPI>
__global__ __launch_bounds__(256) void gemm_bias(
    const float* __restrict__ A, const float* __restrict__ W,
    const float* __restrict__ bias, float* __restrict__ C,
    int M, int N, int K)
{
    __shared__ float As[64][33];
    __shared__ float Ws[64][33];
    const int tid = threadIdx.x;
    const int tx = tid & 15, ty = tid >> 4;
    const int row0 = blockIdx.y * 64, col0 = blockIdx.x * 64;

    float acc[4][4] = {};
    for (int k0 = 0; k0 < K; k0 += 32) {
        #pragma unroll
        for (int l = tid; l < 64 * 32; l += 256) {
            int r = l >> 5, c = l & 31;
            As[r][c] = A[(size_t)(row0 + r) * K + k0 + c];
            Ws[r][c] = W[(size_t)(col0 + r) * K + k0 + c];
        }
        __syncthreads();
        #pragma unroll
        for (int kk = 0; kk < 32; kk++) {
            float a[4], w[4];
            #pragma unroll
            for (int i = 0; i < 4; i++) a[i] = As[ty * 4 + i][kk];
            #pragma unroll
            for (int j = 0; j < 4; j++) w[j] = Ws[tx * 4 + j][kk];
            #pragma unroll
            for (int i = 0; i < 4; i++)
                #pragma unroll
                for (int j = 0; j < 4; j++)
                    acc[i][j] = fmaf(a[i], w[j], acc[i][j]);
        }
        __syncthreads();
    }
    #pragma unroll
    for (int j = 0; j < 4; j++) {
        int col = col0 + tx * 4 + j;
        float bv = bias[col];
        #pragma unroll
        for (int i = 0; i < 4; i++) {
            int row = row0 + ty * 4 + i;
            float v = acc[i][j] + bv;
            if (EPI == 1) v = 0.5f * v * (1.0f + erff(v * 0.70710678118654752f));
            C[(size_t)row * N + col] = v;
        }
    }
}

// ---------------------------------------------------------------------------
// Attention: one wave per (q, h, b). qkv: [B,S,1536] fp32 (q|k|v each 512).
// o: [B,S,512] fp32. HD=64, H=8.
// ---------------------------------------------------------------------------
__global__ __launch_bounds__(64) void attn_kernel(
    const float* __restrict__ qkv, float* __restrict__ o, int S)
{
    const int qi = blockIdx.x, h = blockIdx.y, b = blockIdx.z;
    const int t = threadIdx.x;
    extern __shared__ float smem[];
    float* sc = smem;       // [S]
    float* qv = smem + S;   // [64]

    const float* base = qkv + (size_t)b * S * 1536;
    qv[t] = base[(size_t)qi * 1536 + h * 64 + t];
    __syncthreads();

    const float scale = 0.125f;  // 1/sqrt(64)
    for (int k = t; k < S; k += 64) {
        const float* kp = base + (size_t)k * 1536 + 512 + h * 64;
        float d = 0.f;
        #pragma unroll
        for (int i = 0; i < 64; i++) d = fmaf(qv[i], kp[i], d);
        sc[k] = d * scale;
    }
    __syncthreads();

    float m = -3.0e38f;
    for (int k = t; k < S; k += 64) m = fmaxf(m, sc[k]);
    #pragma unroll
    for (int off = 32; off > 0; off >>= 1) m = fmaxf(m, __shfl_xor(m, off));

    float s = 0.f;
    for (int k = t; k < S; k += 64) { float e = __expf(sc[k] - m); sc[k] = e; s += e; }
    #pragma unroll
    for (int off = 32; off > 0; off >>= 1) s += __shfl_xor(s, off);
    __syncthreads();

    const float inv = 1.0f / s;
    float acc = 0.f;
    for (int k = 0; k < S; k++)
        acc = fmaf(sc[k], base[(size_t)k * 1536 + 1024 + h * 64 + t], acc);
    o[((size_t)b * S + qi) * 512 + h * 64 + t] = acc * inv;
}

// ---------------------------------------------------------------------------
// out = LN(a + b) * g + beta over D=512. One block (256 thr) per row.
// INTERP: b-source is [B,512,512], linearly upsampled to S=1024 rows.
// ---------------------------------------------------------------------------
template <bool INTERP>
__global__ __launch_bounds__(256) void ln_kernel(
    const float* __restrict__ a, const float* __restrict__ bsrc,
    const float* __restrict__ g, const float* __restrict__ beta,
    float* __restrict__ out)
{
    const int row = blockIdx.x;    // b*1024 + s
    const int t = threadIdx.x;
    const size_t base = (size_t)row * 512;

    float a0 = a[base + t], a1 = a[base + t + 256];
    float b0, b1;
    if (INTERP) {
        int s = row & 1023, bb = row >> 10;
        float src = fminf(fmaxf((s + 0.5f) * 0.5f - 0.5f, 0.f), 511.f);
        int i0 = (int)src;              // src >= 0 -> trunc == floor
        int i1 = min(i0 + 1, 511);
        float w = src - (float)i0;
        size_t r0 = ((size_t)bb * 512 + i0) * 512;
        size_t r1 = ((size_t)bb * 512 + i1) * 512;
        b0 = bsrc[r0 + t] * (1.f - w) + bsrc[r1 + t] * w;
        b1 = bsrc[r0 + t + 256] * (1.f - w) + bsrc[r1 + t + 256] * w;
    } else {
        b0 = bsrc[base + t];
        b1 = bsrc[base + t + 256];
    }
    float v0 = a0 + b0, v1 = a1 + b1;

    __shared__ float red[4];
    const int lane = t & 63, wid = t >> 6;

    float sm = v0 + v1;
    #pragma unroll
    for (int off = 32; off > 0; off >>= 1) sm += __shfl_xor(sm, off);
    if (lane == 0) red[wid] = sm;
    __syncthreads();
    sm = red[0] + red[1] + red[2] + red[3];
    const float mean = sm * (1.0f / 512.0f);

    float d0 = v0 - mean, d1 = v1 - mean;
    float vv = d0 * d0 + d1 * d1;
    __syncthreads();   // protect red[] reuse
    #pragma unroll
    for (int off = 32; off > 0; off >>= 1) vv += __shfl_xor(vv, off);
    if (lane == 0) red[wid] = vv;
    __syncthreads();
    vv = red[0] + red[1] + red[2] + red[3];
    const float rstd = rsqrtf(vv * (1.0f / 512.0f) + 1e-5f);

    out[base + t]       = d0 * rstd * g[t]       + beta[t];
    out[base + t + 256] = d1 * rstd * g[t + 256] + beta[t + 256];
}

// ---------------------------------------------------------------------------
// avg_pool1d k=2 s=2 along S: [B,1024,512] -> [B,512,512]
// ---------------------------------------------------------------------------
__global__ __launch_bounds__(256) void pool_kernel(
    const float* __restrict__ x, float* __restrict__ p)
{
    size_t i = (size_t)blockIdx.x * 256 + threadIdx.x;  // 8*512*512 elements
    size_t d = i & 511;
    size_t rs = i >> 9;            // b*512 + s
    size_t b = rs >> 9, s = rs & 511;
    size_t r = (b * 1024 + 2 * s) * 512 + d;
    p[i] = 0.5f * (x[r] + x[r + 512]);
}

// ---------------------------------------------------------------------------
// launch
// ---------------------------------------------------------------------------
extern "C" void kernel_launch(void* const* d_in, const int* in_sizes, int n_in,
                              void* d_out, int out_size, void* d_ws, size_t ws_size,
                              hipStream_t stream)
{
    const float* x      = (const float*)d_in[0];
    const float* w_in1  = (const float*)d_in[1];
    const float* b_in1  = (const float*)d_in[2];
    const float* w_out1 = (const float*)d_in[3];
    const float* b_out1 = (const float*)d_in[4];
    const float* w_in2  = (const float*)d_in[5];
    const float* b_in2  = (const float*)d_in[6];
    const float* w_out2 = (const float*)d_in[7];
    const float* b_out2 = (const float*)d_in[8];
    const float* g1     = (const float*)d_in[9];
    const float* be1    = (const float*)d_in[10];
    const float* g2     = (const float*)d_in[11];
    const float* be2    = (const float*)d_in[12];
    const float* g3     = (const float*)d_in[13];
    const float* be3    = (const float*)d_in[14];
    const float* w_ff1  = (const float*)d_in[15];
    const float* b_ff1  = (const float*)d_in[16];
    const float* w_ff2  = (const float*)d_in[17];
    const float* b_ff2  = (const float*)d_in[18];

    // workspace layout (float elements), lifetimes overlapped; 25,165,824 f = 100.7 MB
    float* ws     = (float*)d_ws;
    float* qkv1   = ws + 0;           // [8,1024,1536] : steps 1-2
    float* o1     = ws + 12582912;    // [8,1024, 512] : steps 2-3
    float* a1     = ws + 0;           // [8,1024, 512] : steps 3-4 (qkv1 dead)
    float* x1     = ws + 16777216;    // [8,1024, 512] : steps 4-9
    float* pooled = ws + 0;           // [8, 512, 512] : steps 5-6 (a1 dead)
    float* qkv2   = ws + 2097152;     // [8, 512,1536] : steps 6-7
    float* o2     = ws + 8388608;     // [8, 512, 512] : steps 7-8
    float* a2     = ws + 10485760;    // [8, 512, 512] : steps 8-9
    float* x2     = ws + 20971520;    // [8,1024, 512] : steps 9-12
    float* h      = ws + 0;           // [8,1024,2048] : steps 10-11 (all low dead)
    float* ff     = ws + 16777216;    // [8,1024, 512] : steps 11-12 (x1 dead)

    dim3 blk(256);

    // 1. qkv1 = x @ w_in1^T + b_in1                       [8192,1536,512]
    gemm_bias<0><<<dim3(24, 128), blk, 0, stream>>>(x, w_in1, b_in1, qkv1, 8192, 1536, 512);
    // 2. o1 = attention(qkv1), S=1024
    attn_kernel<<<dim3(1024, 8, 8), dim3(64), (1024 + 64) * sizeof(float), stream>>>(
        qkv1, o1, 1024);
    // 3. a1 = o1 @ w_out1^T + b_out1                      [8192,512,512]
    gemm_bias<0><<<dim3(8, 128), blk, 0, stream>>>(o1, w_out1, b_out1, a1, 8192, 512, 512);
    // 4. x1 = LN(x + a1; g1, beta1)
    ln_kernel<false><<<8192, blk, 0, stream>>>(x, a1, g1, be1, x1);
    // 5. pooled = avgpool2(x1)
    pool_kernel<<<8192, blk, 0, stream>>>(x1, pooled);
    // 6. qkv2 = pooled @ w_in2^T + b_in2                  [4096,1536,512]
    gemm_bias<0><<<dim3(24, 64), blk, 0, stream>>>(pooled, w_in2, b_in2, qkv2, 4096, 1536, 512);
    // 7. o2 = attention(qkv2), S=512
    attn_kernel<<<dim3(512, 8, 8), dim3(64), (512 + 64) * sizeof(float), stream>>>(
        qkv2, o2, 512);
    // 8. a2 = o2 @ w_out2^T + b_out2                      [4096,512,512]
    gemm_bias<0><<<dim3(8, 64), blk, 0, stream>>>(o2, w_out2, b_out2, a2, 4096, 512, 512);
    // 9. x2 = LN(x1 + interp(a2); g2, beta2)   (interp fused)
    ln_kernel<true><<<8192, blk, 0, stream>>>(x1, a2, g2, be2, x2);
    // 10. h = gelu(x2 @ w_ff1^T + b_ff1)                  [8192,2048,512]
    gemm_bias<1><<<dim3(32, 128), blk, 0, stream>>>(x2, w_ff1, b_ff1, h, 8192, 2048, 512);
    // 11. ff = h @ w_ff2^T + b_ff2                        [8192,512,2048]
    gemm_bias<0><<<dim3(8, 128), blk, 0, stream>>>(h, w_ff2, b_ff2, ff, 8192, 512, 2048);
    // 12. out = LN(x2 + ff; g3, beta3) -> fp32
    ln_kernel<false><<<8192, blk, 0, stream>>>(x2, ff, g3, be3, (float*)d_out);
}

// Round 6
// 2584.466 us; speedup vs baseline: 1.9479x; 1.9479x over previous
//
#include <hip/hip_runtime.h>
#include <hip/hip_bf16.h>
#include <math.h>

// All inputs fp32, output fp32, workspace fp32. fp32 math throughout.

// ---------------------------------------------------------------------------
// GEMM: C[M,N] = act(A[M,K] @ W[N,K]^T + bias[N]); EPI: 0=none, 1=exact GELU
// BM=BN=64, BK=32, 256 threads, 4x4 per thread. M%64==0, N%64==0, K%32==0.
// ---------------------------------------------------------------------------
template <int EPI>
__global__ __launch_bounds__(256) void gemm_bias(
    const float* __restrict__ A, const float* __restrict__ W,
    const float* __restrict__ bias, float* __restrict__ C,
    int M, int N, int K)
{
    __shared__ float As[64][33];
    __shared__ float Ws[64][33];
    const int tid = threadIdx.x;
    const int tx = tid & 15, ty = tid >> 4;
    const int row0 = blockIdx.y * 64, col0 = blockIdx.x * 64;

    float acc[4][4] = {};
    for (int k0 = 0; k0 < K; k0 += 32) {
        #pragma unroll
        for (int l = tid; l < 64 * 32; l += 256) {
            int r = l >> 5, c = l & 31;
            As[r][c] = A[(size_t)(row0 + r) * K + k0 + c];
            Ws[r][c] = W[(size_t)(col0 + r) * K + k0 + c];
        }
        __syncthreads();
        #pragma unroll
        for (int kk = 0; kk < 32; kk++) {
            float a[4], w[4];
            #pragma unroll
            for (int i = 0; i < 4; i++) a[i] = As[ty * 4 + i][kk];
            #pragma unroll
            for (int j = 0; j < 4; j++) w[j] = Ws[tx * 4 + j][kk];
            #pragma unroll
            for (int i = 0; i < 4; i++)
                #pragma unroll
                for (int j = 0; j < 4; j++)
                    acc[i][j] = fmaf(a[i], w[j], acc[i][j]);
        }
        __syncthreads();
    }
    #pragma unroll
    for (int j = 0; j < 4; j++) {
        int col = col0 + tx * 4 + j;
        float bv = bias[col];
        #pragma unroll
        for (int i = 0; i < 4; i++) {
            int row = row0 + ty * 4 + i;
            float v = acc[i][j] + bv;
            if (EPI == 1) v = 0.5f * v * (1.0f + erff(v * 0.70710678118654752f));
            C[(size_t)row * N + col] = v;
        }
    }
}

// ---------------------------------------------------------------------------
// Flash attention: one 256-thr block per (b, h, 64-q tile). qkv [B,S,1536],
// o [B,S,512]. HD=64, H=8. Online softmax; K/V share one LDS buffer.
// LDS: 3 * 64*68*4 = 52224 B -> 3 blocks/CU.
// ---------------------------------------------------------------------------
__global__ __launch_bounds__(256) void flash_attn(
    const float* __restrict__ qkv, float* __restrict__ o, int S)
{
    constexpr int P = 68;                 // row pitch (floats); 68*4 % 16 == 0
    __shared__ float Qs[64 * P];
    __shared__ float KV[64 * P];
    __shared__ float sc[64 * P];

    const int q0 = blockIdx.x * 64, h = blockIdx.y, bb = blockIdx.z;
    const int tid = threadIdx.x;
    const int tx = tid & 15, ty = tid >> 4;

    const float* base = qkv + (size_t)bb * S * 1536 + h * 64;

    // stage Q tile, pre-scaled by 1/sqrt(64)
    for (int idx = tid; idx < 4096; idx += 256) {
        int r = idx >> 6, d = idx & 63;
        Qs[r * P + d] = base[(size_t)(q0 + r) * 1536 + d] * 0.125f;
    }

    float acc[4][4] = {};
    float mrow[4], lrow[4];
    #pragma unroll
    for (int i = 0; i < 4; i++) { mrow[i] = -3.0e38f; lrow[i] = 0.f; }

    const int nchunk = S >> 6;
    for (int c = 0; c < nchunk; ++c) {
        const int k0 = c << 6;
        __syncthreads();   // prior PV done with KV/sc (and Q staged, c==0)

        // stage K chunk [64 keys][64 d]
        for (int idx = tid; idx < 4096; idx += 256) {
            int r = idx >> 6, d = idx & 63;
            KV[r * P + d] = base[(size_t)(k0 + r) * 1536 + 512 + d];
        }
        __syncthreads();

        // scores: s[i][j] = sum_d Q[q0+ty*4+i][d] * K[k0+tx*4+j][d]
        float s[4][4] = {};
        for (int kk = 0; kk < 64; kk += 4) {
            float4 a[4], b[4];
            #pragma unroll
            for (int i = 0; i < 4; i++)
                a[i] = *(const float4*)&Qs[(ty * 4 + i) * P + kk];
            #pragma unroll
            for (int j = 0; j < 4; j++)
                b[j] = *(const float4*)&KV[(tx * 4 + j) * P + kk];
            #pragma unroll
            for (int i = 0; i < 4; i++)
                #pragma unroll
                for (int j = 0; j < 4; j++) {
                    s[i][j] = fmaf(a[i].x, b[j].x, s[i][j]);
                    s[i][j] = fmaf(a[i].y, b[j].y, s[i][j]);
                    s[i][j] = fmaf(a[i].z, b[j].z, s[i][j]);
                    s[i][j] = fmaf(a[i].w, b[j].w, s[i][j]);
                }
        }
        __syncthreads();   // K reads done; KV reusable for V

        // stage V chunk
        for (int idx = tid; idx < 4096; idx += 256) {
            int r = idx >> 6, d = idx & 63;
            KV[r * P + d] = base[(size_t)(k0 + r) * 1536 + 1024 + d];
        }

        // online softmax (row state replicated across the row's 16 lanes)
        #pragma unroll
        for (int i = 0; i < 4; i++) {
            float cm = fmaxf(fmaxf(s[i][0], s[i][1]), fmaxf(s[i][2], s[i][3]));
            #pragma unroll
            for (int off = 1; off < 16; off <<= 1) cm = fmaxf(cm, __shfl_xor(cm, off));
            float mn = fmaxf(mrow[i], cm);
            float alpha = __expf(mrow[i] - mn);
            mrow[i] = mn;
            float4 p;
            p.x = __expf(s[i][0] - mn);
            p.y = __expf(s[i][1] - mn);
            p.z = __expf(s[i][2] - mn);
            p.w = __expf(s[i][3] - mn);
            float ps = p.x + p.y + p.z + p.w;
            #pragma unroll
            for (int off = 1; off < 16; off <<= 1) ps += __shfl_xor(ps, off);
            lrow[i] = lrow[i] * alpha + ps;
            #pragma unroll
            for (int j = 0; j < 4; j++) acc[i][j] *= alpha;
            *(float4*)&sc[(ty * 4 + i) * P + tx * 4] = p;
        }
        __syncthreads();   // V staged, p visible

        // PV: acc[i][j] += sum_k p[q][k] * V[k][d=tx*4+j]
        for (int kk = 0; kk < 64; kk++) {
            float4 v = *(const float4*)&KV[kk * P + tx * 4];
            #pragma unroll
            for (int i = 0; i < 4; i++) {
                float p = sc[(ty * 4 + i) * P + kk];
                acc[i][0] = fmaf(p, v.x, acc[i][0]);
                acc[i][1] = fmaf(p, v.y, acc[i][1]);
                acc[i][2] = fmaf(p, v.z, acc[i][2]);
                acc[i][3] = fmaf(p, v.w, acc[i][3]);
            }
        }
    }

    #pragma unroll
    for (int i = 0; i < 4; i++) {
        float invl = 1.0f / lrow[i];
        float4 r;
        r.x = acc[i][0] * invl; r.y = acc[i][1] * invl;
        r.z = acc[i][2] * invl; r.w = acc[i][3] * invl;
        *(float4*)&o[((size_t)bb * S + q0 + ty * 4 + i) * 512 + h * 64 + tx * 4] = r;
    }
}

// ---------------------------------------------------------------------------
// out = LN(a + b) * g + beta over D=512. One block (256 thr) per row.
// INTERP: b-source is [B,512,512], linearly upsampled to S=1024 rows.
// ---------------------------------------------------------------------------
template <bool INTERP>
__global__ __launch_bounds__(256) void ln_kernel(
    const float* __restrict__ a, const float* __restrict__ bsrc,
    const float* __restrict__ g, const float* __restrict__ beta,
    float* __restrict__ out)
{
    const int row = blockIdx.x;    // b*1024 + s
    const int t = threadIdx.x;
    const size_t base = (size_t)row * 512;

    float a0 = a[base + t], a1 = a[base + t + 256];
    float b0, b1;
    if (INTERP) {
        int s = row & 1023, bb = row >> 10;
        float src = fminf(fmaxf((s + 0.5f) * 0.5f - 0.5f, 0.f), 511.f);
        int i0 = (int)src;              // src >= 0 -> trunc == floor
        int i1 = min(i0 + 1, 511);
        float w = src - (float)i0;
        size_t r0 = ((size_t)bb * 512 + i0) * 512;
        size_t r1 = ((size_t)bb * 512 + i1) * 512;
        b0 = bsrc[r0 + t] * (1.f - w) + bsrc[r1 + t] * w;
        b1 = bsrc[r0 + t + 256] * (1.f - w) + bsrc[r1 + t + 256] * w;
    } else {
        b0 = bsrc[base + t];
        b1 = bsrc[base + t + 256];
    }
    float v0 = a0 + b0, v1 = a1 + b1;

    __shared__ float red[4];
    const int lane = t & 63, wid = t >> 6;

    float sm = v0 + v1;
    #pragma unroll
    for (int off = 32; off > 0; off >>= 1) sm += __shfl_xor(sm, off);
    if (lane == 0) red[wid] = sm;
    __syncthreads();
    sm = red[0] + red[1] + red[2] + red[3];
    const float mean = sm * (1.0f / 512.0f);

    float d0 = v0 - mean, d1 = v1 - mean;
    float vv = d0 * d0 + d1 * d1;
    __syncthreads();   // protect red[] reuse
    #pragma unroll
    for (int off = 32; off > 0; off >>= 1) vv += __shfl_xor(vv, off);
    if (lane == 0) red[wid] = vv;
    __syncthreads();
    vv = red[0] + red[1] + red[2] + red[3];
    const float rstd = rsqrtf(vv * (1.0f / 512.0f) + 1e-5f);

    out[base + t]       = d0 * rstd * g[t]       + beta[t];
    out[base + t + 256] = d1 * rstd * g[t + 256] + beta[t + 256];
}

// ---------------------------------------------------------------------------
// avg_pool1d k=2 s=2 along S: [B,1024,512] -> [B,512,512]
// ---------------------------------------------------------------------------
__global__ __launch_bounds__(256) void pool_kernel(
    const float* __restrict__ x, float* __restrict__ p)
{
    size_t i = (size_t)blockIdx.x * 256 + threadIdx.x;  // 8*512*512 elements
    size_t d = i & 511;
    size_t rs = i >> 9;            // b*512 + s
    size_t b = rs >> 9, s = rs & 511;
    size_t r = (b * 1024 + 2 * s) * 512 + d;
    p[i] = 0.5f * (x[r] + x[r + 512]);
}

// ---------------------------------------------------------------------------
// launch
// ---------------------------------------------------------------------------
extern "C" void kernel_launch(void* const* d_in, const int* in_sizes, int n_in,
                              void* d_out, int out_size, void* d_ws, size_t ws_size,
                              hipStream_t stream)
{
    const float* x      = (const float*)d_in[0];
    const float* w_in1  = (const float*)d_in[1];
    const float* b_in1  = (const float*)d_in[2];
    const float* w_out1 = (const float*)d_in[3];
    const float* b_out1 = (const float*)d_in[4];
    const float* w_in2  = (const float*)d_in[5];
    const float* b_in2  = (const float*)d_in[6];
    const float* w_out2 = (const float*)d_in[7];
    const float* b_out2 = (const float*)d_in[8];
    const float* g1     = (const float*)d_in[9];
    const float* be1    = (const float*)d_in[10];
    const float* g2     = (const float*)d_in[11];
    const float* be2    = (const float*)d_in[12];
    const float* g3     = (const float*)d_in[13];
    const float* be3    = (const float*)d_in[14];
    const float* w_ff1  = (const float*)d_in[15];
    const float* b_ff1  = (const float*)d_in[16];
    const float* w_ff2  = (const float*)d_in[17];
    const float* b_ff2  = (const float*)d_in[18];

    // workspace layout (float elements), lifetimes overlapped; 25,165,824 f = 100.7 MB
    float* ws     = (float*)d_ws;
    float* qkv1   = ws + 0;           // [8,1024,1536] : steps 1-2
    float* o1     = ws + 12582912;    // [8,1024, 512] : steps 2-3
    float* a1     = ws + 0;           // [8,1024, 512] : steps 3-4 (qkv1 dead)
    float* x1     = ws + 16777216;    // [8,1024, 512] : steps 4-9
    float* pooled = ws + 0;           // [8, 512, 512] : steps 5-6 (a1 dead)
    float* qkv2   = ws + 2097152;     // [8, 512,1536] : steps 6-7
    float* o2     = ws + 8388608;     // [8, 512, 512] : steps 7-8
    float* a2     = ws + 10485760;    // [8, 512, 512] : steps 8-9
    float* x2     = ws + 20971520;    // [8,1024, 512] : steps 9-12
    float* h      = ws + 0;           // [8,1024,2048] : steps 10-11 (all low dead)
    float* ff     = ws + 16777216;    // [8,1024, 512] : steps 11-12 (x1 dead)

    dim3 blk(256);

    // 1. qkv1 = x @ w_in1^T + b_in1                       [8192,1536,512]
    gemm_bias<0><<<dim3(24, 128), blk, 0, stream>>>(x, w_in1, b_in1, qkv1, 8192, 1536, 512);
    // 2. o1 = attention(qkv1), S=1024
    flash_attn<<<dim3(16, 8, 8), blk, 0, stream>>>(qkv1, o1, 1024);
    // 3. a1 = o1 @ w_out1^T + b_out1                      [8192,512,512]
    gemm_bias<0><<<dim3(8, 128), blk, 0, stream>>>(o1, w_out1, b_out1, a1, 8192, 512, 512);
    // 4. x1 = LN(x + a1; g1, beta1)
    ln_kernel<false><<<8192, blk, 0, stream>>>(x, a1, g1, be1, x1);
    // 5. pooled = avgpool2(x1)
    pool_kernel<<<8192, blk, 0, stream>>>(x1, pooled);
    // 6. qkv2 = pooled @ w_in2^T + b_in2                  [4096,1536,512]
    gemm_bias<0><<<dim3(24, 64), blk, 0, stream>>>(pooled, w_in2, b_in2, qkv2, 4096, 1536, 512);
    // 7. o2 = attention(qkv2), S=512
    flash_attn<<<dim3(8, 8, 8), blk, 0, stream>>>(qkv2, o2, 512);
    // 8. a2 = o2 @ w_out2^T + b_out2                      [4096,512,512]
    gemm_bias<0><<<dim3(8, 64), blk, 0, stream>>>(o2, w_out2, b_out2, a2, 4096, 512, 512);
    // 9. x2 = LN(x1 + interp(a2); g2, beta2)   (interp fused)
    ln_kernel<true><<<8192, blk, 0, stream>>>(x1, a2, g2, be2, x2);
    // 10. h = gelu(x2 @ w_ff1^T + b_ff1)                  [8192,2048,512]
    gemm_bias<1><<<dim3(32, 128), blk, 0, stream>>>(x2, w_ff1, b_ff1, h, 8192, 2048, 512);
    // 11. ff = h @ w_ff2^T + b_ff2                        [8192,512,2048]
    gemm_bias<0><<<dim3(8, 128), blk, 0, stream>>>(h, w_ff2, b_ff2, ff, 8192, 512, 2048);
    // 12. out = LN(x2 + ff; g3, beta3) -> fp32
    ln_kernel<false><<<8192, blk, 0, stream>>>(x2, ff, g3, be3, (float*)d_out);
}

// Round 7
// 734.097 us; speedup vs baseline: 6.8578x; 3.5206x over previous
//
#include <hip/hip_runtime.h>
#include <hip/hip_bf16.h>
#include <math.h>

typedef __hip_bfloat16 bf16;
typedef __attribute__((ext_vector_type(8))) short short8;   // 8 bf16 = 4 VGPRs
typedef __attribute__((ext_vector_type(4))) float f32x4;    // MFMA acc

__device__ __forceinline__ float ldf(const float* p, size_t i) { return p[i]; }
__device__ __forceinline__ float ldf(const bf16*  p, size_t i) { return __bfloat162float(p[i]); }
__device__ __forceinline__ void  stf(float* p, size_t i, float v) { p[i] = v; }
__device__ __forceinline__ void  stf(bf16*  p, size_t i, float v) { p[i] = __float2bfloat16(v); }

// ---------------------------------------------------------------------------
// fp32 -> bf16 elementwise convert (grid-stride)
// ---------------------------------------------------------------------------
__global__ __launch_bounds__(256) void cvt_kernel(
    const float* __restrict__ src, bf16* __restrict__ dst, int n)
{
    for (int i = blockIdx.x * 256 + threadIdx.x; i < n; i += gridDim.x * 256)
        dst[i] = __float2bfloat16(src[i]);
}

// ---------------------------------------------------------------------------
// MFMA GEMM: C[M,N] = act(A[M,K] @ W[N,K]^T + bias[N]); EPI: 0=none, 1=GELU
// A,W,C bf16; bias fp32. BM=BN=128, BK=64. 256 thr = 4 waves (2x2), 64x64/wave.
// mfma_f32_16x16x32_bf16; frag layout: A[m=lane&15][k=quad*8+j],
// B[k][n=lane&15] (== W[n=lane&15][k]), D: col=lane&15,row=quad*4+reg (m89/m91).
// M%128==0, N%128==0, K%64==0. LDS pitch 72 (+8 pad -> 2-way bank alias, free).
// ---------------------------------------------------------------------------
template <int EPI>
__global__ __launch_bounds__(256) void gemm_mfma(
    const bf16* __restrict__ A, const bf16* __restrict__ W,
    const float* __restrict__ bias, bf16* __restrict__ C,
    int M, int N, int K)
{
    constexpr int LP = 72;
    __shared__ __align__(16) bf16 Asl[128 * LP];
    __shared__ __align__(16) bf16 Bsl[128 * LP];

    const int tid  = threadIdx.x;
    const int lane = tid & 63;
    const int wave = tid >> 6;       // 0..3
    const int wm   = wave >> 1;      // 0..1 : row half
    const int wn   = wave & 1;       // 0..1 : col half
    const int l15  = lane & 15;
    const int quad = lane >> 4;      // 0..3

    const int row0 = blockIdx.y * 128, col0 = blockIdx.x * 128;

    f32x4 acc[4][4] = {};            // [mt][nt]

    for (int k0 = 0; k0 < K; k0 += 64) {
        // stage 128x64 A-tile and B-tile (1024 chunks of 8 bf16 each)
        #pragma unroll
        for (int t = 0; t < 4; t++) {
            int chunk = tid + 256 * t;
            int r = chunk >> 3, c = (chunk & 7) * 8;
            *(short8*)&Asl[r * LP + c] =
                *(const short8*)&A[(size_t)(row0 + r) * K + k0 + c];
            *(short8*)&Bsl[r * LP + c] =
                *(const short8*)&W[(size_t)(col0 + r) * K + k0 + c];
        }
        __syncthreads();

        #pragma unroll
        for (int ks = 0; ks < 64; ks += 32) {
            short8 af[4], bfr[4];
            #pragma unroll
            for (int mt = 0; mt < 4; mt++)
                af[mt] = *(const short8*)&Asl[(wm * 64 + mt * 16 + l15) * LP + ks + quad * 8];
            #pragma unroll
            for (int nt = 0; nt < 4; nt++)
                bfr[nt] = *(const short8*)&Bsl[(wn * 64 + nt * 16 + l15) * LP + ks + quad * 8];
            #pragma unroll
            for (int mt = 0; mt < 4; mt++)
                #pragma unroll
                for (int nt = 0; nt < 4; nt++)
                    acc[mt][nt] = __builtin_amdgcn_mfma_f32_16x16x32_bf16(
                        af[mt], bfr[nt], acc[mt][nt], 0, 0, 0);
        }
        __syncthreads();
    }

    // epilogue: D row = quad*4+reg, col = lane&15 (per 16x16 tile)
    #pragma unroll
    for (int mt = 0; mt < 4; mt++) {
        int row = row0 + wm * 64 + mt * 16 + quad * 4;
        #pragma unroll
        for (int nt = 0; nt < 4; nt++) {
            int col = col0 + wn * 64 + nt * 16 + l15;
            float bv = bias[col];
            #pragma unroll
            for (int r = 0; r < 4; r++) {
                float v = acc[mt][nt][r] + bv;
                if (EPI == 1) v = 0.5f * v * (1.0f + erff(v * 0.70710678118654752f));
                C[(size_t)(row + r) * N + col] = __float2bfloat16(v);
            }
        }
    }
}

// ---------------------------------------------------------------------------
// Flash attention: one 256-thr block per (b, h, 64-q tile). qkv [B,S,1536] bf16,
// o [B,S,512] bf16. HD=64, H=8. Online softmax; K/V share one LDS buffer.
// ---------------------------------------------------------------------------
__global__ __launch_bounds__(256) void flash_attn(
    const bf16* __restrict__ qkv, bf16* __restrict__ o, int S)
{
    constexpr int P = 68;
    __shared__ float Qs[64 * P];
    __shared__ float KV[64 * P];
    __shared__ float sc[64 * P];

    const int q0 = blockIdx.x * 64, h = blockIdx.y, bb = blockIdx.z;
    const int tid = threadIdx.x;
    const int tx = tid & 15, ty = tid >> 4;

    const bf16* base = qkv + (size_t)bb * S * 1536 + h * 64;

    for (int idx = tid; idx < 4096; idx += 256) {
        int r = idx >> 6, d = idx & 63;
        Qs[r * P + d] = __bfloat162float(base[(size_t)(q0 + r) * 1536 + d]) * 0.125f;
    }

    float acc[4][4] = {};
    float mrow[4], lrow[4];
    #pragma unroll
    for (int i = 0; i < 4; i++) { mrow[i] = -3.0e38f; lrow[i] = 0.f; }

    const int nchunk = S >> 6;
    for (int c = 0; c < nchunk; ++c) {
        const int k0 = c << 6;
        __syncthreads();

        for (int idx = tid; idx < 4096; idx += 256) {
            int r = idx >> 6, d = idx & 63;
            KV[r * P + d] = __bfloat162float(base[(size_t)(k0 + r) * 1536 + 512 + d]);
        }
        __syncthreads();

        float s[4][4] = {};
        for (int kk = 0; kk < 64; kk += 4) {
            float4 a[4], b[4];
            #pragma unroll
            for (int i = 0; i < 4; i++)
                a[i] = *(const float4*)&Qs[(ty * 4 + i) * P + kk];
            #pragma unroll
            for (int j = 0; j < 4; j++)
                b[j] = *(const float4*)&KV[(tx * 4 + j) * P + kk];
            #pragma unroll
            for (int i = 0; i < 4; i++)
                #pragma unroll
                for (int j = 0; j < 4; j++) {
                    s[i][j] = fmaf(a[i].x, b[j].x, s[i][j]);
                    s[i][j] = fmaf(a[i].y, b[j].y, s[i][j]);
                    s[i][j] = fmaf(a[i].z, b[j].z, s[i][j]);
                    s[i][j] = fmaf(a[i].w, b[j].w, s[i][j]);
                }
        }
        __syncthreads();

        for (int idx = tid; idx < 4096; idx += 256) {
            int r = idx >> 6, d = idx & 63;
            KV[r * P + d] = __bfloat162float(base[(size_t)(k0 + r) * 1536 + 1024 + d]);
        }

        #pragma unroll
        for (int i = 0; i < 4; i++) {
            float cm = fmaxf(fmaxf(s[i][0], s[i][1]), fmaxf(s[i][2], s[i][3]));
            #pragma unroll
            for (int off = 1; off < 16; off <<= 1) cm = fmaxf(cm, __shfl_xor(cm, off));
            float mn = fmaxf(mrow[i], cm);
            float alpha = __expf(mrow[i] - mn);
            mrow[i] = mn;
            float4 p;
            p.x = __expf(s[i][0] - mn);
            p.y = __expf(s[i][1] - mn);
            p.z = __expf(s[i][2] - mn);
            p.w = __expf(s[i][3] - mn);
            float ps = p.x + p.y + p.z + p.w;
            #pragma unroll
            for (int off = 1; off < 16; off <<= 1) ps += __shfl_xor(ps, off);
            lrow[i] = lrow[i] * alpha + ps;
            #pragma unroll
            for (int j = 0; j < 4; j++) acc[i][j] *= alpha;
            *(float4*)&sc[(ty * 4 + i) * P + tx * 4] = p;
        }
        __syncthreads();

        for (int kk = 0; kk < 64; kk++) {
            float4 v = *(const float4*)&KV[kk * P + tx * 4];
            #pragma unroll
            for (int i = 0; i < 4; i++) {
                float p = sc[(ty * 4 + i) * P + kk];
                acc[i][0] = fmaf(p, v.x, acc[i][0]);
                acc[i][1] = fmaf(p, v.y, acc[i][1]);
                acc[i][2] = fmaf(p, v.z, acc[i][2]);
                acc[i][3] = fmaf(p, v.w, acc[i][3]);
            }
        }
    }

    #pragma unroll
    for (int i = 0; i < 4; i++) {
        float invl = 1.0f / lrow[i];
        size_t ob = ((size_t)bb * S + q0 + ty * 4 + i) * 512 + h * 64 + tx * 4;
        #pragma unroll
        for (int j = 0; j < 4; j++)
            o[ob + j] = __float2bfloat16(acc[i][j] * invl);
    }
}

// ---------------------------------------------------------------------------
// out = LN(a + b) * g + beta over D=512. One block (256 thr) per row.
// INTERP: bsrc is [B,512,512], linearly upsampled to S=1024 rows.
// ---------------------------------------------------------------------------
template <typename AT, typename OT, bool INTERP>
__global__ __launch_bounds__(256) void ln_kernel(
    const AT* __restrict__ a, const bf16* __restrict__ bsrc,
    const float* __restrict__ g, const float* __restrict__ beta,
    OT* __restrict__ out)
{
    const int row = blockIdx.x;    // b*1024 + s
    const int t = threadIdx.x;
    const size_t base = (size_t)row * 512;

    float a0 = ldf(a, base + t), a1 = ldf(a, base + t + 256);
    float b0, b1;
    if (INTERP) {
        int s = row & 1023, bb = row >> 10;
        float src = fminf(fmaxf((s + 0.5f) * 0.5f - 0.5f, 0.f), 511.f);
        int i0 = (int)src;
        int i1 = min(i0 + 1, 511);
        float w = src - (float)i0;
        size_t r0 = ((size_t)bb * 512 + i0) * 512;
        size_t r1 = ((size_t)bb * 512 + i1) * 512;
        b0 = __bfloat162float(bsrc[r0 + t]) * (1.f - w) + __bfloat162float(bsrc[r1 + t]) * w;
        b1 = __bfloat162float(bsrc[r0 + t + 256]) * (1.f - w) + __bfloat162float(bsrc[r1 + t + 256]) * w;
    } else {
        b0 = __bfloat162float(bsrc[base + t]);
        b1 = __bfloat162float(bsrc[base + t + 256]);
    }
    float v0 = a0 + b0, v1 = a1 + b1;

    __shared__ float red[4];
    const int lane = t & 63, wid = t >> 6;

    float sm = v0 + v1;
    #pragma unroll
    for (int off = 32; off > 0; off >>= 1) sm += __shfl_xor(sm, off);
    if (lane == 0) red[wid] = sm;
    __syncthreads();
    sm = red[0] + red[1] + red[2] + red[3];
    const float mean = sm * (1.0f / 512.0f);

    float d0 = v0 - mean, d1 = v1 - mean;
    float vv = d0 * d0 + d1 * d1;
    __syncthreads();
    #pragma unroll
    for (int off = 32; off > 0; off >>= 1) vv += __shfl_xor(vv, off);
    if (lane == 0) red[wid] = vv;
    __syncthreads();
    vv = red[0] + red[1] + red[2] + red[3];
    const float rstd = rsqrtf(vv * (1.0f / 512.0f) + 1e-5f);

    stf(out, base + t,       d0 * rstd * g[t]       + beta[t]);
    stf(out, base + t + 256, d1 * rstd * g[t + 256] + beta[t + 256]);
}

// ---------------------------------------------------------------------------
// avg_pool1d k=2 s=2 along S: [B,1024,512] -> [B,512,512]  (bf16)
// ---------------------------------------------------------------------------
__global__ __launch_bounds__(256) void pool_kernel(
    const bf16* __restrict__ x, bf16* __restrict__ p)
{
    size_t i = (size_t)blockIdx.x * 256 + threadIdx.x;
    size_t d = i & 511;
    size_t rs = i >> 9;
    size_t b = rs >> 9, s = rs & 511;
    size_t r = (b * 1024 + 2 * s) * 512 + d;
    p[i] = __float2bfloat16(0.5f * (__bfloat162float(x[r]) + __bfloat162float(x[r + 512])));
}

// ---------------------------------------------------------------------------
// launch
// ---------------------------------------------------------------------------
extern "C" void kernel_launch(void* const* d_in, const int* in_sizes, int n_in,
                              void* d_out, int out_size, void* d_ws, size_t ws_size,
                              hipStream_t stream)
{
    const float* x      = (const float*)d_in[0];
    const float* w_in1  = (const float*)d_in[1];
    const float* b_in1  = (const float*)d_in[2];
    const float* w_out1 = (const float*)d_in[3];
    const float* b_out1 = (const float*)d_in[4];
    const float* w_in2  = (const float*)d_in[5];
    const float* b_in2  = (const float*)d_in[6];
    const float* w_out2 = (const float*)d_in[7];
    const float* b_out2 = (const float*)d_in[8];
    const float* g1     = (const float*)d_in[9];
    const float* be1    = (const float*)d_in[10];
    const float* g2     = (const float*)d_in[11];
    const float* be2    = (const float*)d_in[12];
    const float* g3     = (const float*)d_in[13];
    const float* be3    = (const float*)d_in[14];
    const float* w_ff1  = (const float*)d_in[15];
    const float* b_ff1  = (const float*)d_in[16];
    const float* w_ff2  = (const float*)d_in[17];
    const float* b_ff2  = (const float*)d_in[18];

    // workspace: bf16 elements; peak 50,331,648 elems = 100.66 MB (proven size)
    bf16* ws     = (bf16*)d_ws;
    bf16* xb     = ws + 0;            // [8,1024, 512]  whole launch
    bf16* wq1    = ws + 4194304;      // [1536,512]     whole launch
    bf16* wo1    = ws + 4980736;      // [512,512]
    bf16* wq2    = ws + 5242880;      // [1536,512]
    bf16* wo2    = ws + 6029312;      // [512,512]
    bf16* wf1    = ws + 6291456;      // [2048,512]
    bf16* wf2    = ws + 7340032;      // [512,2048]
    bf16* qkv1   = ws + 8388608;      // [8,1024,1536]  steps 2-3
    bf16* o1     = ws + 20971520;     // [8,1024, 512]  steps 3-4
    bf16* a1     = ws + 25165824;     // [8,1024, 512]  steps 4-5
    bf16* x1     = ws + 29360128;     // [8,1024, 512]  steps 5-10
    bf16* pooled = ws + 33554432;     // [8, 512, 512]  steps 6-7
    bf16* qkv2   = ws + 35651584;     // [8, 512,1536]  steps 7-8
    bf16* o2     = ws + 41943040;     // [8, 512, 512]  steps 8-9
    bf16* a2     = ws + 44040192;     // [8, 512, 512]  steps 9-10
    bf16* x2     = ws + 46137344;     // [8,1024, 512]  steps 10-13
    bf16* h      = ws + 8388608;      // [8,1024,2048]  steps 11-12 (qkv1/o1 dead)
    bf16* ff     = ws + 25165824;     // [8,1024, 512]  steps 12-13 (a1 dead)

    dim3 blk(256);

    // 0. convert x + weights to bf16
    cvt_kernel<<<1024, blk, 0, stream>>>(x, xb, 4194304);
    cvt_kernel<<<512, blk, 0, stream>>>(w_in1, wq1, 786432);
    cvt_kernel<<<256, blk, 0, stream>>>(w_out1, wo1, 262144);
    cvt_kernel<<<512, blk, 0, stream>>>(w_in2, wq2, 786432);
    cvt_kernel<<<256, blk, 0, stream>>>(w_out2, wo2, 262144);
    cvt_kernel<<<512, blk, 0, stream>>>(w_ff1, wf1, 1048576);
    cvt_kernel<<<512, blk, 0, stream>>>(w_ff2, wf2, 1048576);

    // 1. qkv1 = xb @ wq1^T + b_in1                        [8192,1536,512]
    gemm_mfma<0><<<dim3(12, 64), blk, 0, stream>>>(xb, wq1, b_in1, qkv1, 8192, 1536, 512);
    // 2. o1 = attention(qkv1), S=1024
    flash_attn<<<dim3(16, 8, 8), blk, 0, stream>>>(qkv1, o1, 1024);
    // 3. a1 = o1 @ wo1^T + b_out1                         [8192,512,512]
    gemm_mfma<0><<<dim3(4, 64), blk, 0, stream>>>(o1, wo1, b_out1, a1, 8192, 512, 512);
    // 4. x1 = LN(x + a1; g1, beta1)
    ln_kernel<float, bf16, false><<<8192, blk, 0, stream>>>(x, a1, g1, be1, x1);
    // 5. pooled = avgpool2(x1)
    pool_kernel<<<8192, blk, 0, stream>>>(x1, pooled);
    // 6. qkv2 = pooled @ wq2^T + b_in2                    [4096,1536,512]
    gemm_mfma<0><<<dim3(12, 32), blk, 0, stream>>>(pooled, wq2, b_in2, qkv2, 4096, 1536, 512);
    // 7. o2 = attention(qkv2), S=512
    flash_attn<<<dim3(8, 8, 8), blk, 0, stream>>>(qkv2, o2, 512);
    // 8. a2 = o2 @ wo2^T + b_out2                         [4096,512,512]
    gemm_mfma<0><<<dim3(4, 32), blk, 0, stream>>>(o2, wo2, b_out2, a2, 4096, 512, 512);
    // 9. x2 = LN(x1 + interp(a2); g2, beta2)
    ln_kernel<bf16, bf16, true><<<8192, blk, 0, stream>>>(x1, a2, g2, be2, x2);
    // 10. h = gelu(x2 @ wf1^T + b_ff1)                    [8192,2048,512]
    gemm_mfma<1><<<dim3(16, 64), blk, 0, stream>>>(x2, wf1, b_ff1, h, 8192, 2048, 512);
    // 11. ff = h @ wf2^T + b_ff2                          [8192,512,2048]
    gemm_mfma<0><<<dim3(4, 64), blk, 0, stream>>>(h, wf2, b_ff2, ff, 8192, 512, 2048);
    // 12. out = LN(x2 + ff; g3, beta3) -> fp32
    ln_kernel<bf16, float, false><<<8192, blk, 0, stream>>>(x2, ff, g3, be3, (float*)d_out);
}

// Round 8
// 370.042 us; speedup vs baseline: 13.6047x; 1.9838x over previous
//
#include <hip/hip_runtime.h>
#include <hip/hip_bf16.h>
#include <math.h>

typedef __hip_bfloat16 bf16;
typedef __attribute__((ext_vector_type(8))) short short8;   // 8 bf16 = 4 VGPRs
typedef __attribute__((ext_vector_type(4))) float f32x4;    // MFMA acc

__device__ __forceinline__ float ldf(const float* p, size_t i) { return p[i]; }
__device__ __forceinline__ float ldf(const bf16*  p, size_t i) { return __bfloat162float(p[i]); }
__device__ __forceinline__ void  stf(float* p, size_t i, float v) { p[i] = v; }
__device__ __forceinline__ void  stf(bf16*  p, size_t i, float v) { p[i] = __float2bfloat16(v); }

// ---------------------------------------------------------------------------
// fp32 -> bf16 elementwise convert (grid-stride)
// ---------------------------------------------------------------------------
__global__ __launch_bounds__(256) void cvt_kernel(
    const float* __restrict__ src, bf16* __restrict__ dst, int n)
{
    for (int i = blockIdx.x * 256 + threadIdx.x; i < n; i += gridDim.x * 256)
        dst[i] = __float2bfloat16(src[i]);
}

// ---------------------------------------------------------------------------
// MFMA GEMM: C[M,N] = act(A[M,K] @ W[N,K]^T + bias[N]); EPI: 0=none, 1=GELU
// BM=BN=128, BK=64. 256 thr = 4 waves (2x2), 64x64/wave. 16x16x32_bf16.
// ---------------------------------------------------------------------------
template <int EPI>
__global__ __launch_bounds__(256) void gemm_mfma(
    const bf16* __restrict__ A, const bf16* __restrict__ W,
    const float* __restrict__ bias, bf16* __restrict__ C,
    int M, int N, int K)
{
    constexpr int LP = 72;
    __shared__ __align__(16) bf16 Asl[128 * LP];
    __shared__ __align__(16) bf16 Bsl[128 * LP];

    const int tid  = threadIdx.x;
    const int lane = tid & 63;
    const int wave = tid >> 6;
    const int wm   = wave >> 1;
    const int wn   = wave & 1;
    const int l15  = lane & 15;
    const int quad = lane >> 4;

    const int row0 = blockIdx.y * 128, col0 = blockIdx.x * 128;

    f32x4 acc[4][4] = {};

    for (int k0 = 0; k0 < K; k0 += 64) {
        #pragma unroll
        for (int t = 0; t < 4; t++) {
            int chunk = tid + 256 * t;
            int r = chunk >> 3, c = (chunk & 7) * 8;
            *(short8*)&Asl[r * LP + c] =
                *(const short8*)&A[(size_t)(row0 + r) * K + k0 + c];
            *(short8*)&Bsl[r * LP + c] =
                *(const short8*)&W[(size_t)(col0 + r) * K + k0 + c];
        }
        __syncthreads();

        #pragma unroll
        for (int ks = 0; ks < 64; ks += 32) {
            short8 af[4], bfr[4];
            #pragma unroll
            for (int mt = 0; mt < 4; mt++)
                af[mt] = *(const short8*)&Asl[(wm * 64 + mt * 16 + l15) * LP + ks + quad * 8];
            #pragma unroll
            for (int nt = 0; nt < 4; nt++)
                bfr[nt] = *(const short8*)&Bsl[(wn * 64 + nt * 16 + l15) * LP + ks + quad * 8];
            #pragma unroll
            for (int mt = 0; mt < 4; mt++)
                #pragma unroll
                for (int nt = 0; nt < 4; nt++)
                    acc[mt][nt] = __builtin_amdgcn_mfma_f32_16x16x32_bf16(
                        af[mt], bfr[nt], acc[mt][nt], 0, 0, 0);
        }
        __syncthreads();
    }

    #pragma unroll
    for (int mt = 0; mt < 4; mt++) {
        int row = row0 + wm * 64 + mt * 16 + quad * 4;
        #pragma unroll
        for (int nt = 0; nt < 4; nt++) {
            int col = col0 + wn * 64 + nt * 16 + l15;
            float bv = bias[col];
            #pragma unroll
            for (int r = 0; r < 4; r++) {
                float v = acc[mt][nt][r] + bv;
                if (EPI == 1) v = 0.5f * v * (1.0f + erff(v * 0.70710678118654752f));
                C[(size_t)(row + r) * N + col] = __float2bfloat16(v);
            }
        }
    }
}

// ---------------------------------------------------------------------------
// MFMA flash attention. Block = 256 thr = 4 waves per (b, h, 64-q tile);
// wave handles 16 q rows. S^T = K@Q^T (mfma, natural layouts), online softmax
// on C/D layout (q = lane&15), P -> LDS roundtrip -> A-frag, PV with V^T LDS.
// qkv [B,S,1536] bf16, o [B,S,512] bf16. HD=64, H=8.
// ---------------------------------------------------------------------------
__global__ __launch_bounds__(256) void flash_attn_mfma(
    const bf16* __restrict__ qkv, bf16* __restrict__ o, int S)
{
    __shared__ __align__(16) bf16 Ks[64 * 72];      // K chunk [k][d]
    __shared__ __align__(16) bf16 Vt[64 * 68];      // V chunk transposed [d][k]
    __shared__ __align__(16) bf16 Pl[4][16 * 72];   // per-wave P [q][k]
    __shared__ float aX[4][16];                     // per-wave q-indexed exchange

    const int tid = threadIdx.x;
    const int wave = tid >> 6, lane = tid & 63;
    const int l15 = lane & 15, quad = lane >> 4;
    const int q0 = blockIdx.x * 64, h = blockIdx.y, bb = blockIdx.z;
    const bf16* base = qkv + (size_t)bb * S * 1536 + h * 64;

    // Q B-frags in registers for the whole kernel (q row = q0 + wave*16 + l15)
    const size_t qoff = (size_t)(q0 + wave * 16 + l15) * 1536;
    short8 qf0 = *(const short8*)&base[qoff + quad * 8];
    short8 qf1 = *(const short8*)&base[qoff + 32 + quad * 8];

    f32x4 oacc[4] = {};                  // O d-tiles: row=q=quad*4+r, col=d=l15
    float mrow = -3.0e38f, lrow = 0.f;   // state for q = l15 (replicated / quad)

    for (int k0 = 0; k0 < S; k0 += 64) {
        __syncthreads();   // prior chunk's Ks/Vt reads complete

        // stage K [64][64] -> Ks (pitch 72, 16B-aligned rows)
        #pragma unroll
        for (int t = 0; t < 2; t++) {
            int c = tid + 256 * t;
            int r = c >> 3, col = (c & 7) * 8;
            *(short8*)&Ks[r * 72 + col] =
                *(const short8*)&base[(size_t)(k0 + r) * 1536 + 512 + col];
        }
        // stage V transposed -> Vt[d*68 + k]; lane = d (coalesced 128B loads)
        #pragma unroll
        for (int i = 0; i < 16; i++) {
            int r = i * 4 + wave;
            Vt[lane * 68 + r] = base[(size_t)(k0 + r) * 1536 + 1024 + lane];
        }
        __syncthreads();

        // S^T[64k][16q]: 4 m-tiles of 16x16, k-dim = d (2 steps of 32)
        f32x4 st[4] = {};
        #pragma unroll
        for (int mt = 0; mt < 4; mt++) {
            short8 kf0 = *(const short8*)&Ks[(mt * 16 + l15) * 72 + quad * 8];
            short8 kf1 = *(const short8*)&Ks[(mt * 16 + l15) * 72 + 32 + quad * 8];
            st[mt] = __builtin_amdgcn_mfma_f32_16x16x32_bf16(kf0, qf0, st[mt], 0, 0, 0);
            st[mt] = __builtin_amdgcn_mfma_f32_16x16x32_bf16(kf1, qf1, st[mt], 0, 0, 0);
        }

        // online softmax for q = l15; st[mt][r] = S^T[mt*16+quad*4+r][l15]
        float cm = -3.0e38f;
        #pragma unroll
        for (int mt = 0; mt < 4; mt++)
            #pragma unroll
            for (int r = 0; r < 4; r++) {
                st[mt][r] *= 0.125f;
                cm = fmaxf(cm, st[mt][r]);
            }
        cm = fmaxf(cm, __shfl_xor(cm, 16));
        cm = fmaxf(cm, __shfl_xor(cm, 32));
        float mn = fmaxf(mrow, cm);
        float alpha = __expf(mrow - mn);
        mrow = mn;

        float ps = 0.f;
        #pragma unroll
        for (int mt = 0; mt < 4; mt++)
            #pragma unroll
            for (int r = 0; r < 4; r++) {
                float p = __expf(st[mt][r] - mn);
                ps += p;
                Pl[wave][l15 * 72 + mt * 16 + quad * 4 + r] = __float2bfloat16(p);
            }
        ps += __shfl_xor(ps, 16);
        ps += __shfl_xor(ps, 32);
        lrow = lrow * alpha + ps;

        // broadcast alpha from q=l15 lanes to q=quad*4+r consumers (same wave)
        if (quad == 0) aX[wave][l15] = alpha;
        float a4[4];
        #pragma unroll
        for (int r = 0; r < 4; r++) a4[r] = aX[wave][quad * 4 + r];
        #pragma unroll
        for (int nt = 0; nt < 4; nt++)
            #pragma unroll
            for (int r = 0; r < 4; r++) oacc[nt][r] *= a4[r];

        // PV: O[16q][64d] += P[16q][64k] @ V[64k][64d]
        #pragma unroll
        for (int kb = 0; kb < 2; kb++) {
            short8 pf = *(const short8*)&Pl[wave][l15 * 72 + kb * 32 + quad * 8];
            #pragma unroll
            for (int nt = 0; nt < 4; nt++) {
                // B-frag: V^T[d = nt*16+l15][k = kb*32+quad*8 + j], 2x b64
                const bf16* vp = &Vt[(nt * 16 + l15) * 68 + kb * 32 + quad * 8];
                short8 vf;
                *(long*)&vf = *(const long*)vp;
                *((long*)&vf + 1) = *(const long*)(vp + 4);
                oacc[nt] = __builtin_amdgcn_mfma_f32_16x16x32_bf16(pf, vf, oacc[nt], 0, 0, 0);
            }
        }
    }

    // final 1/l, exchanged q=l15 -> q=quad*4+r (same wave)
    if (quad == 0) aX[wave][l15] = 1.0f / lrow;
    float iv[4];
    #pragma unroll
    for (int r = 0; r < 4; r++) iv[r] = aX[wave][quad * 4 + r];

    #pragma unroll
    for (int nt = 0; nt < 4; nt++)
        #pragma unroll
        for (int r = 0; r < 4; r++) {
            size_t row = (size_t)bb * S + q0 + wave * 16 + quad * 4 + r;
            o[row * 512 + h * 64 + nt * 16 + l15] = __float2bfloat16(oacc[nt][r] * iv[r]);
        }
}

// ---------------------------------------------------------------------------
// out = LN(a + b) * g + beta over D=512. One block (256 thr) per row.
// ---------------------------------------------------------------------------
template <typename AT, typename OT, bool INTERP>
__global__ __launch_bounds__(256) void ln_kernel(
    const AT* __restrict__ a, const bf16* __restrict__ bsrc,
    const float* __restrict__ g, const float* __restrict__ beta,
    OT* __restrict__ out)
{
    const int row = blockIdx.x;
    const int t = threadIdx.x;
    const size_t base = (size_t)row * 512;

    float a0 = ldf(a, base + t), a1 = ldf(a, base + t + 256);
    float b0, b1;
    if (INTERP) {
        int s = row & 1023, bb = row >> 10;
        float src = fminf(fmaxf((s + 0.5f) * 0.5f - 0.5f, 0.f), 511.f);
        int i0 = (int)src;
        int i1 = min(i0 + 1, 511);
        float w = src - (float)i0;
        size_t r0 = ((size_t)bb * 512 + i0) * 512;
        size_t r1 = ((size_t)bb * 512 + i1) * 512;
        b0 = __bfloat162float(bsrc[r0 + t]) * (1.f - w) + __bfloat162float(bsrc[r1 + t]) * w;
        b1 = __bfloat162float(bsrc[r0 + t + 256]) * (1.f - w) + __bfloat162float(bsrc[r1 + t + 256]) * w;
    } else {
        b0 = __bfloat162float(bsrc[base + t]);
        b1 = __bfloat162float(bsrc[base + t + 256]);
    }
    float v0 = a0 + b0, v1 = a1 + b1;

    __shared__ float red[4];
    const int lane = t & 63, wid = t >> 6;

    float sm = v0 + v1;
    #pragma unroll
    for (int off = 32; off > 0; off >>= 1) sm += __shfl_xor(sm, off);
    if (lane == 0) red[wid] = sm;
    __syncthreads();
    sm = red[0] + red[1] + red[2] + red[3];
    const float mean = sm * (1.0f / 512.0f);

    float d0 = v0 - mean, d1 = v1 - mean;
    float vv = d0 * d0 + d1 * d1;
    __syncthreads();
    #pragma unroll
    for (int off = 32; off > 0; off >>= 1) vv += __shfl_xor(vv, off);
    if (lane == 0) red[wid] = vv;
    __syncthreads();
    vv = red[0] + red[1] + red[2] + red[3];
    const float rstd = rsqrtf(vv * (1.0f / 512.0f) + 1e-5f);

    stf(out, base + t,       d0 * rstd * g[t]       + beta[t]);
    stf(out, base + t + 256, d1 * rstd * g[t + 256] + beta[t + 256]);
}

// ---------------------------------------------------------------------------
// avg_pool1d k=2 s=2 along S: [B,1024,512] -> [B,512,512]  (bf16)
// ---------------------------------------------------------------------------
__global__ __launch_bounds__(256) void pool_kernel(
    const bf16* __restrict__ x, bf16* __restrict__ p)
{
    size_t i = (size_t)blockIdx.x * 256 + threadIdx.x;
    size_t d = i & 511;
    size_t rs = i >> 9;
    size_t b = rs >> 9, s = rs & 511;
    size_t r = (b * 1024 + 2 * s) * 512 + d;
    p[i] = __float2bfloat16(0.5f * (__bfloat162float(x[r]) + __bfloat162float(x[r + 512])));
}

// ---------------------------------------------------------------------------
// launch
// ---------------------------------------------------------------------------
extern "C" void kernel_launch(void* const* d_in, const int* in_sizes, int n_in,
                              void* d_out, int out_size, void* d_ws, size_t ws_size,
                              hipStream_t stream)
{
    const float* x      = (const float*)d_in[0];
    const float* w_in1  = (const float*)d_in[1];
    const float* b_in1  = (const float*)d_in[2];
    const float* w_out1 = (const float*)d_in[3];
    const float* b_out1 = (const float*)d_in[4];
    const float* w_in2  = (const float*)d_in[5];
    const float* b_in2  = (const float*)d_in[6];
    const float* w_out2 = (const float*)d_in[7];
    const float* b_out2 = (const float*)d_in[8];
    const float* g1     = (const float*)d_in[9];
    const float* be1    = (const float*)d_in[10];
    const float* g2     = (const float*)d_in[11];
    const float* be2    = (const float*)d_in[12];
    const float* g3     = (const float*)d_in[13];
    const float* be3    = (const float*)d_in[14];
    const float* w_ff1  = (const float*)d_in[15];
    const float* b_ff1  = (const float*)d_in[16];
    const float* w_ff2  = (const float*)d_in[17];
    const float* b_ff2  = (const float*)d_in[18];

    // workspace: bf16 elements; peak 50,331,648 elems = 100.66 MB (proven size)
    bf16* ws     = (bf16*)d_ws;
    bf16* xb     = ws + 0;            // [8,1024, 512]
    bf16* wq1    = ws + 4194304;      // [1536,512]
    bf16* wo1    = ws + 4980736;      // [512,512]
    bf16* wq2    = ws + 5242880;      // [1536,512]
    bf16* wo2    = ws + 6029312;      // [512,512]
    bf16* wf1    = ws + 6291456;      // [2048,512]
    bf16* wf2    = ws + 7340032;      // [512,2048]
    bf16* qkv1   = ws + 8388608;      // [8,1024,1536]
    bf16* o1     = ws + 20971520;     // [8,1024, 512]
    bf16* a1     = ws + 25165824;     // [8,1024, 512]
    bf16* x1     = ws + 29360128;     // [8,1024, 512]
    bf16* pooled = ws + 33554432;     // [8, 512, 512]
    bf16* qkv2   = ws + 35651584;     // [8, 512,1536]
    bf16* o2     = ws + 41943040;     // [8, 512, 512]
    bf16* a2     = ws + 44040192;     // [8, 512, 512]
    bf16* x2     = ws + 46137344;     // [8,1024, 512]
    bf16* h      = ws + 8388608;      // [8,1024,2048] (qkv1/o1 dead)
    bf16* ff     = ws + 25165824;     // [8,1024, 512] (a1 dead)

    dim3 blk(256);

    cvt_kernel<<<1024, blk, 0, stream>>>(x, xb, 4194304);
    cvt_kernel<<<512, blk, 0, stream>>>(w_in1, wq1, 786432);
    cvt_kernel<<<256, blk, 0, stream>>>(w_out1, wo1, 262144);
    cvt_kernel<<<512, blk, 0, stream>>>(w_in2, wq2, 786432);
    cvt_kernel<<<256, blk, 0, stream>>>(w_out2, wo2, 262144);
    cvt_kernel<<<512, blk, 0, stream>>>(w_ff1, wf1, 1048576);
    cvt_kernel<<<512, blk, 0, stream>>>(w_ff2, wf2, 1048576);

    gemm_mfma<0><<<dim3(12, 64), blk, 0, stream>>>(xb, wq1, b_in1, qkv1, 8192, 1536, 512);
    flash_attn_mfma<<<dim3(16, 8, 8), blk, 0, stream>>>(qkv1, o1, 1024);
    gemm_mfma<0><<<dim3(4, 64), blk, 0, stream>>>(o1, wo1, b_out1, a1, 8192, 512, 512);
    ln_kernel<float, bf16, false><<<8192, blk, 0, stream>>>(x, a1, g1, be1, x1);
    pool_kernel<<<8192, blk, 0, stream>>>(x1, pooled);
    gemm_mfma<0><<<dim3(12, 32), blk, 0, stream>>>(pooled, wq2, b_in2, qkv2, 4096, 1536, 512);
    flash_attn_mfma<<<dim3(8, 8, 8), blk, 0, stream>>>(qkv2, o2, 512);
    gemm_mfma<0><<<dim3(4, 32), blk, 0, stream>>>(o2, wo2, b_out2, a2, 4096, 512, 512);
    ln_kernel<bf16, bf16, true><<<8192, blk, 0, stream>>>(x1, a2, g2, be2, x2);
    gemm_mfma<1><<<dim3(16, 64), blk, 0, stream>>>(x2, wf1, b_ff1, h, 8192, 2048, 512);
    gemm_mfma<0><<<dim3(4, 64), blk, 0, stream>>>(h, wf2, b_ff2, ff, 8192, 512, 2048);
    ln_kernel<bf16, float, false><<<8192, blk, 0, stream>>>(x2, ff, g3, be3, (float*)d_out);
}

// Round 10
// 366.888 us; speedup vs baseline: 13.7217x; 1.0086x over previous
//
#include <hip/hip_runtime.h>
#include <hip/hip_bf16.h>
#include <math.h>

typedef __hip_bfloat16 bf16;
typedef __attribute__((ext_vector_type(8))) short short8;   // 8 bf16 = 4 VGPRs
typedef __attribute__((ext_vector_type(4))) short s4v;      // 4 bf16 = 8 B
typedef __attribute__((ext_vector_type(4))) float f32x4;    // MFMA acc

__device__ __forceinline__ float ldf(const float* p, size_t i) { return p[i]; }
__device__ __forceinline__ float ldf(const bf16*  p, size_t i) { return __bfloat162float(p[i]); }
__device__ __forceinline__ void  stf(float* p, size_t i, float v) { p[i] = v; }
__device__ __forceinline__ void  stf(bf16*  p, size_t i, float v) { p[i] = __float2bfloat16(v); }

__device__ __forceinline__ float ex2(float x) { return __builtin_amdgcn_exp2f(x); }

// async global->LDS, 16 B per lane; dest = wave-uniform base + lane*16 (m97/m104)
__device__ __forceinline__ void gl16(const void* gp, void* lp) {
    __builtin_amdgcn_global_load_lds(
        (const __attribute__((address_space(1))) void*)gp,
        (__attribute__((address_space(3))) void*)lp, 16, 0, 0);
}

// ---------------------------------------------------------------------------
// fp32 -> bf16 convert (grid-stride)
// ---------------------------------------------------------------------------
__global__ __launch_bounds__(256) void cvt_kernel(
    const float* __restrict__ src, bf16* __restrict__ dst, int n)
{
    for (int i = blockIdx.x * 256 + threadIdx.x; i < n; i += gridDim.x * 256)
        dst[i] = __float2bfloat16(src[i]);
}

// all 6 weight matrices -> one contiguous bf16 region (4,194,304 elems)
__global__ __launch_bounds__(256) void cvt_w(
    const float* __restrict__ s0, const float* __restrict__ s1,
    const float* __restrict__ s2, const float* __restrict__ s3,
    const float* __restrict__ s4, const float* __restrict__ s5,
    bf16* __restrict__ dst)
{
    int i = blockIdx.x * 256 + threadIdx.x;
    const float* s; int off;
    if      (i <  786432) { s = s0; off = 0; }
    else if (i < 1048576) { s = s1; off =  786432; }
    else if (i < 1835008) { s = s2; off = 1048576; }
    else if (i < 2097152) { s = s3; off = 1835008; }
    else if (i < 3145728) { s = s4; off = 2097152; }
    else                  { s = s5; off = 3145728; }
    dst[i] = __float2bfloat16(s[i - off]);
}

// ---------------------------------------------------------------------------
// MFMA GEMM, m97 structure: BM=BN=128, BK=64, LP=64 (unpadded),
// global_load_lds width=16 staging. 256 thr = 4 waves (2x2), 64x64/wave.
// C[M,N] = act(A[M,K] @ W[N,K]^T + bias[N]); EPI: 0=none, 1=exact GELU.
// ---------------------------------------------------------------------------
template <int EPI>
__global__ __launch_bounds__(256) void gemm_mfma(
    const bf16* __restrict__ A, const bf16* __restrict__ W,
    const float* __restrict__ bias, bf16* __restrict__ C,
    int M, int N, int K)
{
    __shared__ __align__(16) bf16 Asl[128 * 64];
    __shared__ __align__(16) bf16 Bsl[128 * 64];

    const int tid  = threadIdx.x;
    const int lane = tid & 63;
    const int wave = tid >> 6;
    const int wm   = wave >> 1;
    const int wn   = wave & 1;
    const int l15  = lane & 15;
    const int quad = lane >> 4;
    const int sr   = lane >> 3;        // row-within-8 for staging
    const int sc   = (lane & 7) * 8;   // col for staging

    const int row0 = blockIdx.y * 128, col0 = blockIdx.x * 128;

    f32x4 acc[4][4] = {};

    for (int k0 = 0; k0 < K; k0 += 64) {
        __syncthreads();               // prior MFMA reads done before overwrite
        #pragma unroll
        for (int t = 0; t < 4; t++) {
            int r0 = wave * 32 + t * 8;            // wave-uniform
            int r  = r0 + sr;
            gl16(&A[(size_t)(row0 + r) * K + k0 + sc], &Asl[r0 * 64]);
            gl16(&W[(size_t)(col0 + r) * K + k0 + sc], &Bsl[r0 * 64]);
        }
        __syncthreads();               // compiler drains vmcnt here

        #pragma unroll
        for (int ks = 0; ks < 64; ks += 32) {
            short8 af[4], bfr[4];
            #pragma unroll
            for (int mt = 0; mt < 4; mt++)
                af[mt] = *(const short8*)&Asl[(wm * 64 + mt * 16 + l15) * 64 + ks + quad * 8];
            #pragma unroll
            for (int nt = 0; nt < 4; nt++)
                bfr[nt] = *(const short8*)&Bsl[(wn * 64 + nt * 16 + l15) * 64 + ks + quad * 8];
            #pragma unroll
            for (int mt = 0; mt < 4; mt++)
                #pragma unroll
                for (int nt = 0; nt < 4; nt++)
                    acc[mt][nt] = __builtin_amdgcn_mfma_f32_16x16x32_bf16(
                        af[mt], bfr[nt], acc[mt][nt], 0, 0, 0);
        }
    }

    #pragma unroll
    for (int mt = 0; mt < 4; mt++) {
        int row = row0 + wm * 64 + mt * 16 + quad * 4;
        #pragma unroll
        for (int nt = 0; nt < 4; nt++) {
            int col = col0 + wn * 64 + nt * 16 + l15;
            float bv = bias[col];
            #pragma unroll
            for (int r = 0; r < 4; r++) {
                float v = acc[mt][nt][r] + bv;
                if (EPI == 1) v = 0.5f * v * (1.0f + erff(v * 0.70710678118654752f));
                C[(size_t)(row + r) * N + col] = __float2bfloat16(v);
            }
        }
    }
}

// ---------------------------------------------------------------------------
// MFMA flash attention. Block = 4 waves, each handling NS 16-q sub-tiles
// (block q-tile = 64*NS). S^T = K@Q^T, online softmax in exp2 domain with
// the 1/8 scale folded in, P packed to LDS (b64), PV with V^T LDS.
// ---------------------------------------------------------------------------
template <int NS>
__global__ __launch_bounds__(256) void flash_attn_mfma(
    const bf16* __restrict__ qkv, bf16* __restrict__ o, int S)
{
    __shared__ __align__(16) bf16 Ks[64 * 72];
    __shared__ __align__(16) bf16 Vt[64 * 68];
    __shared__ __align__(16) bf16 Pl[4][NS * 16 * 72];
    __shared__ float aX[4][NS * 16];

    const int tid = threadIdx.x;
    const int wave = tid >> 6, lane = tid & 63;
    const int l15 = lane & 15, quad = lane >> 4;
    const int q0 = blockIdx.x * (64 * NS), h = blockIdx.y, bb = blockIdx.z;
    const bf16* base = qkv + (size_t)bb * S * 1536 + h * 64;

    short8 qf[NS][2];
    #pragma unroll
    for (int s = 0; s < NS; s++) {
        size_t qoff = (size_t)(q0 + (wave * NS + s) * 16 + l15) * 1536;
        qf[s][0] = *(const short8*)&base[qoff + quad * 8];
        qf[s][1] = *(const short8*)&base[qoff + 32 + quad * 8];
    }

    f32x4 oacc[NS][4] = {};
    float mrow[NS], lrow[NS];
    #pragma unroll
    for (int s = 0; s < NS; s++) { mrow[s] = -3.0e38f; lrow[s] = 0.f; }

    const float CE = 0.18033688f;   // 0.125 * log2(e)

    for (int k0 = 0; k0 < S; k0 += 64) {
        __syncthreads();

        #pragma unroll
        for (int t = 0; t < 2; t++) {
            int c = tid + 256 * t;
            int r = c >> 3, col = (c & 7) * 8;
            *(short8*)&Ks[r * 72 + col] =
                *(const short8*)&base[(size_t)(k0 + r) * 1536 + 512 + col];
        }
        #pragma unroll
        for (int i = 0; i < 8; i++) {
            int r = (wave * 8 + i) * 2;
            union { bf16 b[2]; unsigned u; } pk;
            pk.b[0] = base[(size_t)(k0 + r) * 1536 + 1024 + lane];
            pk.b[1] = base[(size_t)(k0 + r + 1) * 1536 + 1024 + lane];
            *(unsigned*)&Vt[lane * 68 + r] = pk.u;
        }
        __syncthreads();

        // S^T (raw scores): k-frag load hoisted over sub-tiles
        f32x4 st[NS][4] = {};
        #pragma unroll
        for (int mt = 0; mt < 4; mt++) {
            short8 kf0 = *(const short8*)&Ks[(mt * 16 + l15) * 72 + quad * 8];
            short8 kf1 = *(const short8*)&Ks[(mt * 16 + l15) * 72 + 32 + quad * 8];
            #pragma unroll
            for (int s = 0; s < NS; s++) {
                st[s][mt] = __builtin_amdgcn_mfma_f32_16x16x32_bf16(kf0, qf[s][0], st[s][mt], 0, 0, 0);
                st[s][mt] = __builtin_amdgcn_mfma_f32_16x16x32_bf16(kf1, qf[s][1], st[s][mt], 0, 0, 0);
            }
        }

        #pragma unroll
        for (int s = 0; s < NS; s++) {
            float cm = -3.0e38f;
            #pragma unroll
            for (int mt = 0; mt < 4; mt++)
                #pragma unroll
                for (int r = 0; r < 4; r++) cm = fmaxf(cm, st[s][mt][r]);
            cm = fmaxf(cm, __shfl_xor(cm, 16));
            cm = fmaxf(cm, __shfl_xor(cm, 32));
            float mn = fmaxf(mrow[s], cm);
            float alpha = ex2((mrow[s] - mn) * CE);
            mrow[s] = mn;
            float mb = mn * CE;
            float ps = 0.f;
            #pragma unroll
            for (int mt = 0; mt < 4; mt++) {
                s4v pw;
                #pragma unroll
                for (int r = 0; r < 4; r++) {
                    float p = ex2(st[s][mt][r] * CE - mb);
                    ps += p;
                    union { bf16 b; short h; } cv;
                    cv.b = __float2bfloat16(p);
                    pw[r] = cv.h;
                }
                *(s4v*)&Pl[wave][(s * 16 + l15) * 72 + mt * 16 + quad * 4] = pw;
            }
            ps += __shfl_xor(ps, 16);
            ps += __shfl_xor(ps, 32);
            lrow[s] = lrow[s] * alpha + ps;
            if (quad == 0) aX[wave][s * 16 + l15] = alpha;
        }

        // rescale O by alpha (q = quad*4+r view)
        #pragma unroll
        for (int s = 0; s < NS; s++) {
            float a4[4];
            #pragma unroll
            for (int r = 0; r < 4; r++) a4[r] = aX[wave][s * 16 + quad * 4 + r];
            #pragma unroll
            for (int nt = 0; nt < 4; nt++)
                #pragma unroll
                for (int r = 0; r < 4; r++) oacc[s][nt][r] *= a4[r];
        }

        // PV
        #pragma unroll
        for (int kb = 0; kb < 2; kb++) {
            short8 pf[NS];
            #pragma unroll
            for (int s = 0; s < NS; s++)
                pf[s] = *(const short8*)&Pl[wave][(s * 16 + l15) * 72 + kb * 32 + quad * 8];
            #pragma unroll
            for (int nt = 0; nt < 4; nt++) {
                const bf16* vp = &Vt[(nt * 16 + l15) * 68 + kb * 32 + quad * 8];
                short8 vf;
                *(long*)&vf = *(const long*)vp;
                *((long*)&vf + 1) = *(const long*)(vp + 4);
                #pragma unroll
                for (int s = 0; s < NS; s++)
                    oacc[s][nt] = __builtin_amdgcn_mfma_f32_16x16x32_bf16(pf[s], vf, oacc[s][nt], 0, 0, 0);
            }
        }
    }

    #pragma unroll
    for (int s = 0; s < NS; s++)
        if (quad == 0) aX[wave][s * 16 + l15] = 1.0f / lrow[s];
    #pragma unroll
    for (int s = 0; s < NS; s++) {
        float iv[4];
        #pragma unroll
        for (int r = 0; r < 4; r++) iv[r] = aX[wave][s * 16 + quad * 4 + r];
        #pragma unroll
        for (int nt = 0; nt < 4; nt++)
            #pragma unroll
            for (int r = 0; r < 4; r++) {
                size_t row = (size_t)bb * S + q0 + (wave * NS + s) * 16 + quad * 4 + r;
                o[row * 512 + h * 64 + nt * 16 + l15] = __float2bfloat16(oacc[s][nt][r] * iv[r]);
            }
    }
}

// ---------------------------------------------------------------------------
// out = LN(a + b) * g + beta over D=512. One block (256 thr) per row.
// ---------------------------------------------------------------------------
template <typename AT, typename OT, bool INTERP>
__global__ __launch_bounds__(256) void ln_kernel(
    const AT* __restrict__ a, const bf16* __restrict__ bsrc,
    const float* __restrict__ g, const float* __restrict__ beta,
    OT* __restrict__ out)
{
    const int row = blockIdx.x;
    const int t = threadIdx.x;
    const size_t base = (size_t)row * 512;

    float a0 = ldf(a, base + t), a1 = ldf(a, base + t + 256);
    float b0, b1;
    if (INTERP) {
        int s = row & 1023, bb = row >> 10;
        float src = fminf(fmaxf((s + 0.5f) * 0.5f - 0.5f, 0.f), 511.f);
        int i0 = (int)src;
        int i1 = min(i0 + 1, 511);
        float w = src - (float)i0;
        size_t r0 = ((size_t)bb * 512 + i0) * 512;
        size_t r1 = ((size_t)bb * 512 + i1) * 512;
        b0 = __bfloat162float(bsrc[r0 + t]) * (1.f - w) + __bfloat162float(bsrc[r1 + t]) * w;
        b1 = __bfloat162float(bsrc[r0 + t + 256]) * (1.f - w) + __bfloat162float(bsrc[r1 + t + 256]) * w;
    } else {
        b0 = __bfloat162float(bsrc[base + t]);
        b1 = __bfloat162float(bsrc[base + t + 256]);
    }
    float v0 = a0 + b0, v1 = a1 + b1;

    __shared__ float red[4];
    const int lane = t & 63, wid = t >> 6;

    float sm = v0 + v1;
    #pragma unroll
    for (int off = 32; off > 0; off >>= 1) sm += __shfl_xor(sm, off);
    if (lane == 0) red[wid] = sm;
    __syncthreads();
    sm = red[0] + red[1] + red[2] + red[3];
    const float mean = sm * (1.0f / 512.0f);

    float d0 = v0 - mean, d1 = v1 - mean;
    float vv = d0 * d0 + d1 * d1;
    __syncthreads();
    #pragma unroll
    for (int off = 32; off > 0; off >>= 1) vv += __shfl_xor(vv, off);
    if (lane == 0) red[wid] = vv;
    __syncthreads();
    vv = red[0] + red[1] + red[2] + red[3];
    const float rstd = rsqrtf(vv * (1.0f / 512.0f) + 1e-5f);

    stf(out, base + t,       d0 * rstd * g[t]       + beta[t]);
    stf(out, base + t + 256, d1 * rstd * g[t + 256] + beta[t + 256]);
}

// ---------------------------------------------------------------------------
// avg_pool1d k=2 s=2 along S: [B,1024,512] -> [B,512,512]  (bf16)
// ---------------------------------------------------------------------------
__global__ __launch_bounds__(256) void pool_kernel(
    const bf16* __restrict__ x, bf16* __restrict__ p)
{
    size_t i = (size_t)blockIdx.x * 256 + threadIdx.x;
    size_t d = i & 511;
    size_t rs = i >> 9;
    size_t b = rs >> 9, s = rs & 511;
    size_t r = (b * 1024 + 2 * s) * 512 + d;
    p[i] = __float2bfloat16(0.5f * (__bfloat162float(x[r]) + __bfloat162float(x[r + 512])));
}

// ---------------------------------------------------------------------------
// launch
// ---------------------------------------------------------------------------
extern "C" void kernel_launch(void* const* d_in, const int* in_sizes, int n_in,
                              void* d_out, int out_size, void* d_ws, size_t ws_size,
                              hipStream_t stream)
{
    const float* x      = (const float*)d_in[0];
    const float* w_in1  = (const float*)d_in[1];
    const float* b_in1  = (const float*)d_in[2];
    const float* w_out1 = (const float*)d_in[3];
    const float* b_out1 = (const float*)d_in[4];
    const float* w_in2  = (const float*)d_in[5];
    const float* b_in2  = (const float*)d_in[6];
    const float* w_out2 = (const float*)d_in[7];
    const float* b_out2 = (const float*)d_in[8];
    const float* g1     = (const float*)d_in[9];
    const float* be1    = (const float*)d_in[10];
    const float* g2     = (const float*)d_in[11];
    const float* be2    = (const float*)d_in[12];
    const float* g3     = (const float*)d_in[13];
    const float* be3    = (const float*)d_in[14];
    const float* w_ff1  = (const float*)d_in[15];
    const float* b_ff1  = (const float*)d_in[16];
    const float* w_ff2  = (const float*)d_in[17];
    const float* b_ff2  = (const float*)d_in[18];

    // workspace: bf16 elements; peak 50,331,648 elems = 100.66 MB (proven size)
    bf16* ws     = (bf16*)d_ws;
    bf16* xb     = ws + 0;            // [8,1024, 512]
    bf16* wq1    = ws + 4194304;      // [1536,512]   -- weights contiguous:
    bf16* wo1    = ws + 4980736;      // [512,512]
    bf16* wq2    = ws + 5242880;      // [1536,512]
    bf16* wo2    = ws + 6029312;      // [512,512]
    bf16* wf1    = ws + 6291456;      // [2048,512]
    bf16* wf2    = ws + 7340032;      // [512,2048]
    bf16* qkv1   = ws + 8388608;      // [8,1024,1536]
    bf16* o1     = ws + 20971520;     // [8,1024, 512]
    bf16* a1     = ws + 25165824;     // [8,1024, 512]
    bf16* x1     = ws + 29360128;     // [8,1024, 512]
    bf16* pooled = ws + 33554432;     // [8, 512, 512]
    bf16* qkv2   = ws + 35651584;     // [8, 512,1536]
    bf16* o2     = ws + 41943040;     // [8, 512, 512]
    bf16* a2     = ws + 44040192;     // [8, 512, 512]
    bf16* x2     = ws + 46137344;     // [8,1024, 512]
    bf16* h      = ws + 8388608;      // [8,1024,2048] (qkv1/o1 dead)
    bf16* ff     = ws + 25165824;     // [8,1024, 512] (a1 dead)

    dim3 blk(256);

    cvt_kernel<<<4096, blk, 0, stream>>>(x, xb, 4194304);
    cvt_w<<<16384, blk, 0, stream>>>(w_in1, w_out1, w_in2, w_out2, w_ff1, w_ff2, wq1);

    gemm_mfma<0><<<dim3(12, 64), blk, 0, stream>>>(xb, wq1, b_in1, qkv1, 8192, 1536, 512);
    flash_attn_mfma<2><<<dim3(8, 8, 8), blk, 0, stream>>>(qkv1, o1, 1024);
    gemm_mfma<0><<<dim3(4, 64), blk, 0, stream>>>(o1, wo1, b_out1, a1, 8192, 512, 512);
    ln_kernel<float, bf16, false><<<8192, blk, 0, stream>>>(x, a1, g1, be1, x1);
    pool_kernel<<<8192, blk, 0, stream>>>(x1, pooled);
    gemm_mfma<0><<<dim3(12, 32), blk, 0, stream>>>(pooled, wq2, b_in2, qkv2, 4096, 1536, 512);
    flash_attn_mfma<1><<<dim3(8, 8, 8), blk, 0, stream>>>(qkv2, o2, 512);
    gemm_mfma<0><<<dim3(4, 32), blk, 0, stream>>>(o2, wo2, b_out2, a2, 4096, 512, 512);
    ln_kernel<bf16, bf16, true><<<8192, blk, 0, stream>>>(x1, a2, g2, be2, x2);
    gemm_mfma<1><<<dim3(16, 64), blk, 0, stream>>>(x2, wf1, b_ff1, h, 8192, 2048, 512);
    gemm_mfma<0><<<dim3(4, 64), blk, 0, stream>>>(h, wf2, b_ff2, ff, 8192, 512, 2048);
    ln_kernel<bf16, float, false><<<8192, blk, 0, stream>>>(x2, ff, g3, be3, (float*)d_out);
}

// Round 11
// 338.064 us; speedup vs baseline: 14.8916x; 1.0853x over previous
//
#include <hip/hip_runtime.h>
#include <hip/hip_bf16.h>
#include <math.h>

typedef __hip_bfloat16 bf16;
typedef __attribute__((ext_vector_type(8))) short short8;   // 8 bf16 = 4 VGPRs
typedef __attribute__((ext_vector_type(4))) short s4v;      // 4 bf16 = 8 B
typedef __attribute__((ext_vector_type(4))) float f32x4;    // MFMA acc

__device__ __forceinline__ float ldf(const float* p, size_t i) { return p[i]; }
__device__ __forceinline__ float ldf(const bf16*  p, size_t i) { return __bfloat162float(p[i]); }
__device__ __forceinline__ void  stf(float* p, size_t i, float v) { p[i] = v; }
__device__ __forceinline__ void  stf(bf16*  p, size_t i, float v) { p[i] = __float2bfloat16(v); }

__device__ __forceinline__ float ex2(float x) { return __builtin_amdgcn_exp2f(x); }

// async global->LDS, 16 B per lane; dest = wave-uniform base + lane*16 (m97/m104)
__device__ __forceinline__ void gl16(const void* gp, void* lp) {
    __builtin_amdgcn_global_load_lds(
        (const __attribute__((address_space(1))) void*)gp,
        (__attribute__((address_space(3))) void*)lp, 16, 0, 0);
}

// ---------------------------------------------------------------------------
// fp32 -> bf16 convert (grid-stride)
// ---------------------------------------------------------------------------
__global__ __launch_bounds__(256) void cvt_kernel(
    const float* __restrict__ src, bf16* __restrict__ dst, int n)
{
    for (int i = blockIdx.x * 256 + threadIdx.x; i < n; i += gridDim.x * 256)
        dst[i] = __float2bfloat16(src[i]);
}

// all 6 weight matrices -> one contiguous bf16 region (4,194,304 elems)
__global__ __launch_bounds__(256) void cvt_w(
    const float* __restrict__ s0, const float* __restrict__ s1,
    const float* __restrict__ s2, const float* __restrict__ s3,
    const float* __restrict__ s4, const float* __restrict__ s5,
    bf16* __restrict__ dst)
{
    int i = blockIdx.x * 256 + threadIdx.x;
    const float* s; int off;
    if      (i <  786432) { s = s0; off = 0; }
    else if (i < 1048576) { s = s1; off =  786432; }
    else if (i < 1835008) { s = s2; off = 1048576; }
    else if (i < 2097152) { s = s3; off = 1835008; }
    else if (i < 3145728) { s = s4; off = 2097152; }
    else                  { s = s5; off = 3145728; }
    dst[i] = __float2bfloat16(s[i - off]);
}

// ---------------------------------------------------------------------------
// MFMA GEMM: BM=BN=128, BK=64, XOR-swizzled LDS (group g at g^(row&7)) +
// double-buffered async global_load_lds prefetch. 4 waves (2x2), 64x64/wave.
// C[M,N] = act(A[M,K] @ W[N,K]^T + bias[N]); EPI: 0=none, 1=exact GELU.
// ---------------------------------------------------------------------------
template <int EPI>
__global__ __launch_bounds__(256) void gemm_mfma(
    const bf16* __restrict__ A, const bf16* __restrict__ W,
    const float* __restrict__ bias, bf16* __restrict__ C,
    int M, int N, int K)
{
    __shared__ __align__(16) bf16 Asl[2][128 * 64];
    __shared__ __align__(16) bf16 Bsl[2][128 * 64];

    const int tid  = threadIdx.x;
    const int lane = tid & 63;
    const int wave = tid >> 6;
    const int wm   = wave >> 1;
    const int wn   = wave & 1;
    const int l15  = lane & 15;
    const int quad = lane >> 4;
    const int sr   = lane >> 3;                 // staging row within 8
    const int sc   = ((lane & 7) ^ sr) * 8;     // swizzled source column

    const int row0 = blockIdx.y * 128, col0 = blockIdx.x * 128;

    f32x4 acc[4][4] = {};

    const int nk = K >> 6;

    // prologue: stage tile 0 -> buf 0
    #pragma unroll
    for (int t = 0; t < 4; t++) {
        int r0 = wave * 32 + t * 8;             // wave-uniform, multiple of 8
        gl16(&A[(size_t)(row0 + r0 + sr) * K + sc], &Asl[0][r0 * 64]);
        gl16(&W[(size_t)(col0 + r0 + sr) * K + sc], &Bsl[0][r0 * 64]);
    }

    int cur = 0;
    for (int i = 0; i < nk; i++) {
        __syncthreads();   // drains vmcnt for buf[cur]; prior reads of buf[cur^1] done
        if (i + 1 < nk) {
            int k1 = (i + 1) << 6;
            #pragma unroll
            for (int t = 0; t < 4; t++) {
                int r0 = wave * 32 + t * 8;
                gl16(&A[(size_t)(row0 + r0 + sr) * K + k1 + sc], &Asl[cur ^ 1][r0 * 64]);
                gl16(&W[(size_t)(col0 + r0 + sr) * K + k1 + sc], &Bsl[cur ^ 1][r0 * 64]);
            }
        }

        #pragma unroll
        for (int ks = 0; ks < 64; ks += 32) {
            short8 af[4], bfr[4];
            const int g0 = (ks >> 3) + quad;
            const int col = (g0 ^ (l15 & 7)) * 8;   // un-swizzle on read
            #pragma unroll
            for (int mt = 0; mt < 4; mt++)
                af[mt] = *(const short8*)&Asl[cur][(wm * 64 + mt * 16 + l15) * 64 + col];
            #pragma unroll
            for (int nt = 0; nt < 4; nt++)
                bfr[nt] = *(const short8*)&Bsl[cur][(wn * 64 + nt * 16 + l15) * 64 + col];
            #pragma unroll
            for (int mt = 0; mt < 4; mt++)
                #pragma unroll
                for (int nt = 0; nt < 4; nt++)
                    acc[mt][nt] = __builtin_amdgcn_mfma_f32_16x16x32_bf16(
                        af[mt], bfr[nt], acc[mt][nt], 0, 0, 0);
        }
        cur ^= 1;
    }

    #pragma unroll
    for (int mt = 0; mt < 4; mt++) {
        int row = row0 + wm * 64 + mt * 16 + quad * 4;
        #pragma unroll
        for (int nt = 0; nt < 4; nt++) {
            int col = col0 + wn * 64 + nt * 16 + l15;
            float bv = bias[col];
            #pragma unroll
            for (int r = 0; r < 4; r++) {
                float v = acc[mt][nt][r] + bv;
                if (EPI == 1) v = 0.5f * v * (1.0f + erff(v * 0.70710678118654752f));
                C[(size_t)(row + r) * N + col] = __float2bfloat16(v);
            }
        }
    }
}

// ---------------------------------------------------------------------------
// MFMA flash attention (unchanged from round 10). Block = 4 waves, each with
// NS 16-q sub-tiles. S^T = K@Q^T, online softmax (exp2 domain), PV with V^T.
// ---------------------------------------------------------------------------
template <int NS>
__global__ __launch_bounds__(256) void flash_attn_mfma(
    const bf16* __restrict__ qkv, bf16* __restrict__ o, int S)
{
    __shared__ __align__(16) bf16 Ks[64 * 72];
    __shared__ __align__(16) bf16 Vt[64 * 68];
    __shared__ __align__(16) bf16 Pl[4][NS * 16 * 72];
    __shared__ float aX[4][NS * 16];

    const int tid = threadIdx.x;
    const int wave = tid >> 6, lane = tid & 63;
    const int l15 = lane & 15, quad = lane >> 4;
    const int q0 = blockIdx.x * (64 * NS), h = blockIdx.y, bb = blockIdx.z;
    const bf16* base = qkv + (size_t)bb * S * 1536 + h * 64;

    short8 qf[NS][2];
    #pragma unroll
    for (int s = 0; s < NS; s++) {
        size_t qoff = (size_t)(q0 + (wave * NS + s) * 16 + l15) * 1536;
        qf[s][0] = *(const short8*)&base[qoff + quad * 8];
        qf[s][1] = *(const short8*)&base[qoff + 32 + quad * 8];
    }

    f32x4 oacc[NS][4] = {};
    float mrow[NS], lrow[NS];
    #pragma unroll
    for (int s = 0; s < NS; s++) { mrow[s] = -3.0e38f; lrow[s] = 0.f; }

    const float CE = 0.18033688f;   // 0.125 * log2(e)

    for (int k0 = 0; k0 < S; k0 += 64) {
        __syncthreads();

        #pragma unroll
        for (int t = 0; t < 2; t++) {
            int c = tid + 256 * t;
            int r = c >> 3, col = (c & 7) * 8;
            *(short8*)&Ks[r * 72 + col] =
                *(const short8*)&base[(size_t)(k0 + r) * 1536 + 512 + col];
        }
        #pragma unroll
        for (int i = 0; i < 8; i++) {
            int r = (wave * 8 + i) * 2;
            union { bf16 b[2]; unsigned u; } pk;
            pk.b[0] = base[(size_t)(k0 + r) * 1536 + 1024 + lane];
            pk.b[1] = base[(size_t)(k0 + r + 1) * 1536 + 1024 + lane];
            *(unsigned*)&Vt[lane * 68 + r] = pk.u;
        }
        __syncthreads();

        f32x4 st[NS][4] = {};
        #pragma unroll
        for (int mt = 0; mt < 4; mt++) {
            short8 kf0 = *(const short8*)&Ks[(mt * 16 + l15) * 72 + quad * 8];
            short8 kf1 = *(const short8*)&Ks[(mt * 16 + l15) * 72 + 32 + quad * 8];
            #pragma unroll
            for (int s = 0; s < NS; s++) {
                st[s][mt] = __builtin_amdgcn_mfma_f32_16x16x32_bf16(kf0, qf[s][0], st[s][mt], 0, 0, 0);
                st[s][mt] = __builtin_amdgcn_mfma_f32_16x16x32_bf16(kf1, qf[s][1], st[s][mt], 0, 0, 0);
            }
        }

        #pragma unroll
        for (int s = 0; s < NS; s++) {
            float cm = -3.0e38f;
            #pragma unroll
            for (int mt = 0; mt < 4; mt++)
                #pragma unroll
                for (int r = 0; r < 4; r++) cm = fmaxf(cm, st[s][mt][r]);
            cm = fmaxf(cm, __shfl_xor(cm, 16));
            cm = fmaxf(cm, __shfl_xor(cm, 32));
            float mn = fmaxf(mrow[s], cm);
            float alpha = ex2((mrow[s] - mn) * CE);
            mrow[s] = mn;
            float mb = mn * CE;
            float ps = 0.f;
            #pragma unroll
            for (int mt = 0; mt < 4; mt++) {
                s4v pw;
                #pragma unroll
                for (int r = 0; r < 4; r++) {
                    float p = ex2(st[s][mt][r] * CE - mb);
                    ps += p;
                    union { bf16 b; short h; } cv;
                    cv.b = __float2bfloat16(p);
                    pw[r] = cv.h;
                }
                *(s4v*)&Pl[wave][(s * 16 + l15) * 72 + mt * 16 + quad * 4] = pw;
            }
            ps += __shfl_xor(ps, 16);
            ps += __shfl_xor(ps, 32);
            lrow[s] = lrow[s] * alpha + ps;
            if (quad == 0) aX[wave][s * 16 + l15] = alpha;
        }

        #pragma unroll
        for (int s = 0; s < NS; s++) {
            float a4[4];
            #pragma unroll
            for (int r = 0; r < 4; r++) a4[r] = aX[wave][s * 16 + quad * 4 + r];
            #pragma unroll
            for (int nt = 0; nt < 4; nt++)
                #pragma unroll
                for (int r = 0; r < 4; r++) oacc[s][nt][r] *= a4[r];
        }

        #pragma unroll
        for (int kb = 0; kb < 2; kb++) {
            short8 pf[NS];
            #pragma unroll
            for (int s = 0; s < NS; s++)
                pf[s] = *(const short8*)&Pl[wave][(s * 16 + l15) * 72 + kb * 32 + quad * 8];
            #pragma unroll
            for (int nt = 0; nt < 4; nt++) {
                const bf16* vp = &Vt[(nt * 16 + l15) * 68 + kb * 32 + quad * 8];
                short8 vf;
                *(long*)&vf = *(const long*)vp;
                *((long*)&vf + 1) = *(const long*)(vp + 4);
                #pragma unroll
                for (int s = 0; s < NS; s++)
                    oacc[s][nt] = __builtin_amdgcn_mfma_f32_16x16x32_bf16(pf[s], vf, oacc[s][nt], 0, 0, 0);
            }
        }
    }

    #pragma unroll
    for (int s = 0; s < NS; s++)
        if (quad == 0) aX[wave][s * 16 + l15] = 1.0f / lrow[s];
    #pragma unroll
    for (int s = 0; s < NS; s++) {
        float iv[4];
        #pragma unroll
        for (int r = 0; r < 4; r++) iv[r] = aX[wave][s * 16 + quad * 4 + r];
        #pragma unroll
        for (int nt = 0; nt < 4; nt++)
            #pragma unroll
            for (int r = 0; r < 4; r++) {
                size_t row = (size_t)bb * S + q0 + (wave * NS + s) * 16 + quad * 4 + r;
                o[row * 512 + h * 64 + nt * 16 + l15] = __float2bfloat16(oacc[s][nt][r] * iv[r]);
            }
    }
}

// ---------------------------------------------------------------------------
// out = LN(a + b) * g + beta over D=512. One block (256 thr) per row.
// ---------------------------------------------------------------------------
template <typename AT, typename OT, bool INTERP>
__global__ __launch_bounds__(256) void ln_kernel(
    const AT* __restrict__ a, const bf16* __restrict__ bsrc,
    const float* __restrict__ g, const float* __restrict__ beta,
    OT* __restrict__ out)
{
    const int row = blockIdx.x;
    const int t = threadIdx.x;
    const size_t base = (size_t)row * 512;

    float a0 = ldf(a, base + t), a1 = ldf(a, base + t + 256);
    float b0, b1;
    if (INTERP) {
        int s = row & 1023, bb = row >> 10;
        float src = fminf(fmaxf((s + 0.5f) * 0.5f - 0.5f, 0.f), 511.f);
        int i0 = (int)src;
        int i1 = min(i0 + 1, 511);
        float w = src - (float)i0;
        size_t r0 = ((size_t)bb * 512 + i0) * 512;
        size_t r1 = ((size_t)bb * 512 + i1) * 512;
        b0 = __bfloat162float(bsrc[r0 + t]) * (1.f - w) + __bfloat162float(bsrc[r1 + t]) * w;
        b1 = __bfloat162float(bsrc[r0 + t + 256]) * (1.f - w) + __bfloat162float(bsrc[r1 + t + 256]) * w;
    } else {
        b0 = __bfloat162float(bsrc[base + t]);
        b1 = __bfloat162float(bsrc[base + t + 256]);
    }
    float v0 = a0 + b0, v1 = a1 + b1;

    __shared__ float red[4];
    const int lane = t & 63, wid = t >> 6;

    float sm = v0 + v1;
    #pragma unroll
    for (int off = 32; off > 0; off >>= 1) sm += __shfl_xor(sm, off);
    if (lane == 0) red[wid] = sm;
    __syncthreads();
    sm = red[0] + red[1] + red[2] + red[3];
    const float mean = sm * (1.0f / 512.0f);

    float d0 = v0 - mean, d1 = v1 - mean;
    float vv = d0 * d0 + d1 * d1;
    __syncthreads();
    #pragma unroll
    for (int off = 32; off > 0; off >>= 1) vv += __shfl_xor(vv, off);
    if (lane == 0) red[wid] = vv;
    __syncthreads();
    vv = red[0] + red[1] + red[2] + red[3];
    const float rstd = rsqrtf(vv * (1.0f / 512.0f) + 1e-5f);

    stf(out, base + t,       d0 * rstd * g[t]       + beta[t]);
    stf(out, base + t + 256, d1 * rstd * g[t + 256] + beta[t + 256]);
}

// ---------------------------------------------------------------------------
// avg_pool1d k=2 s=2 along S: [B,1024,512] -> [B,512,512]  (bf16)
// ---------------------------------------------------------------------------
__global__ __launch_bounds__(256) void pool_kernel(
    const bf16* __restrict__ x, bf16* __restrict__ p)
{
    size_t i = (size_t)blockIdx.x * 256 + threadIdx.x;
    size_t d = i & 511;
    size_t rs = i >> 9;
    size_t b = rs >> 9, s = rs & 511;
    size_t r = (b * 1024 + 2 * s) * 512 + d;
    p[i] = __float2bfloat16(0.5f * (__bfloat162float(x[r]) + __bfloat162float(x[r + 512])));
}

// ---------------------------------------------------------------------------
// launch
// ---------------------------------------------------------------------------
extern "C" void kernel_launch(void* const* d_in, const int* in_sizes, int n_in,
                              void* d_out, int out_size, void* d_ws, size_t ws_size,
                              hipStream_t stream)
{
    const float* x      = (const float*)d_in[0];
    const float* w_in1  = (const float*)d_in[1];
    const float* b_in1  = (const float*)d_in[2];
    const float* w_out1 = (const float*)d_in[3];
    const float* b_out1 = (const float*)d_in[4];
    const float* w_in2  = (const float*)d_in[5];
    const float* b_in2  = (const float*)d_in[6];
    const float* w_out2 = (const float*)d_in[7];
    const float* b_out2 = (const float*)d_in[8];
    const float* g1     = (const float*)d_in[9];
    const float* be1    = (const float*)d_in[10];
    const float* g2     = (const float*)d_in[11];
    const float* be2    = (const float*)d_in[12];
    const float* g3     = (const float*)d_in[13];
    const float* be3    = (const float*)d_in[14];
    const float* w_ff1  = (const float*)d_in[15];
    const float* b_ff1  = (const float*)d_in[16];
    const float* w_ff2  = (const float*)d_in[17];
    const float* b_ff2  = (const float*)d_in[18];

    // workspace: bf16 elements; peak 50,331,648 elems = 100.66 MB (proven size)
    bf16* ws     = (bf16*)d_ws;
    bf16* xb     = ws + 0;            // [8,1024, 512]
    bf16* wq1    = ws + 4194304;      // [1536,512]   -- weights contiguous:
    bf16* wo1    = ws + 4980736;      // [512,512]
    bf16* wq2    = ws + 5242880;      // [1536,512]
    bf16* wo2    = ws + 6029312;      // [512,512]
    bf16* wf1    = ws + 6291456;      // [2048,512]
    bf16* wf2    = ws + 7340032;      // [512,2048]
    bf16* qkv1   = ws + 8388608;      // [8,1024,1536]
    bf16* o1     = ws + 20971520;     // [8,1024, 512]
    bf16* a1     = ws + 25165824;     // [8,1024, 512]
    bf16* x1     = ws + 29360128;     // [8,1024, 512]
    bf16* pooled = ws + 33554432;     // [8, 512, 512]
    bf16* qkv2   = ws + 35651584;     // [8, 512,1536]
    bf16* o2     = ws + 41943040;     // [8, 512, 512]
    bf16* a2     = ws + 44040192;     // [8, 512, 512]
    bf16* x2     = ws + 46137344;     // [8,1024, 512]
    bf16* h      = ws + 8388608;      // [8,1024,2048] (qkv1/o1 dead)
    bf16* ff     = ws + 25165824;     // [8,1024, 512] (a1 dead)

    dim3 blk(256);

    cvt_kernel<<<4096, blk, 0, stream>>>(x, xb, 4194304);
    cvt_w<<<16384, blk, 0, stream>>>(w_in1, w_out1, w_in2, w_out2, w_ff1, w_ff2, wq1);

    gemm_mfma<0><<<dim3(12, 64), blk, 0, stream>>>(xb, wq1, b_in1, qkv1, 8192, 1536, 512);
    flash_attn_mfma<2><<<dim3(8, 8, 8), blk, 0, stream>>>(qkv1, o1, 1024);
    gemm_mfma<0><<<dim3(4, 64), blk, 0, stream>>>(o1, wo1, b_out1, a1, 8192, 512, 512);
    ln_kernel<float, bf16, false><<<8192, blk, 0, stream>>>(x, a1, g1, be1, x1);
    pool_kernel<<<8192, blk, 0, stream>>>(x1, pooled);
    gemm_mfma<0><<<dim3(12, 32), blk, 0, stream>>>(pooled, wq2, b_in2, qkv2, 4096, 1536, 512);
    flash_attn_mfma<1><<<dim3(8, 8, 8), blk, 0, stream>>>(qkv2, o2, 512);
    gemm_mfma<0><<<dim3(4, 32), blk, 0, stream>>>(o2, wo2, b_out2, a2, 4096, 512, 512);
    ln_kernel<bf16, bf16, true><<<8192, blk, 0, stream>>>(x1, a2, g2, be2, x2);
    gemm_mfma<1><<<dim3(16, 64), blk, 0, stream>>>(x2, wf1, b_ff1, h, 8192, 2048, 512);
    gemm_mfma<0><<<dim3(4, 64), blk, 0, stream>>>(h, wf2, b_ff2, ff, 8192, 512, 2048);
    ln_kernel<bf16, float, false><<<8192, blk, 0, stream>>>(x2, ff, g3, be3, (float*)d_out);
}